// Round 8
// baseline (911.898 us; speedup 1.0000x reference)
//
#include <hip/hip_runtime.h>
#include <hip/hip_bf16.h>
#include <hip/hip_cooperative_groups.h>
#include <math.h>

namespace cg = cooperative_groups;

typedef __attribute__((ext_vector_type(8))) short short8;
typedef __attribute__((ext_vector_type(8))) unsigned short ushort8;
typedef __attribute__((ext_vector_type(4))) unsigned short ushort4v;
typedef __attribute__((ext_vector_type(4))) float f32x4;

// ---------------------------------------------------------------------------
// JAX threefry2x32 (20 rounds) — verified bit-exact vs jax.random in R1.
// ---------------------------------------------------------------------------
__host__ __device__ inline void threefry2x32(unsigned k0, unsigned k1,
                                             unsigned x0, unsigned x1,
                                             unsigned* out0, unsigned* out1) {
  unsigned ks0 = k0, ks1 = k1, ks2 = k0 ^ k1 ^ 0x1BD11BDAu;
  x0 += ks0; x1 += ks1;
#define TF_ROUND(r) { x0 += x1; x1 = (x1 << (r)) | (x1 >> (32 - (r))); x1 ^= x0; }
  TF_ROUND(13) TF_ROUND(15) TF_ROUND(26) TF_ROUND(6)
  x0 += ks1; x1 += ks2 + 1u;
  TF_ROUND(17) TF_ROUND(29) TF_ROUND(16) TF_ROUND(24)
  x0 += ks2; x1 += ks0 + 2u;
  TF_ROUND(13) TF_ROUND(15) TF_ROUND(26) TF_ROUND(6)
  x0 += ks0; x1 += ks1 + 3u;
  TF_ROUND(17) TF_ROUND(29) TF_ROUND(16) TF_ROUND(24)
  x0 += ks1; x1 += ks2 + 4u;
  TF_ROUND(13) TF_ROUND(15) TF_ROUND(26) TF_ROUND(6)
  x0 += ks2; x1 += ks0 + 5u;
#undef TF_ROUND
  *out0 = x0; *out1 = x1;
}

__device__ inline float jax_uniform01(unsigned key0, unsigned key1, unsigned i) {
  unsigned o0, o1;
  threefry2x32(key0, key1, 0u, i, &o0, &o1);
  unsigned bits = o0 ^ o1;
  return __uint_as_float((bits >> 9) | 0x3f800000u) - 1.0f;
}

__device__ inline unsigned short f2bf(float f) {
  unsigned u = __float_as_uint(f);
  u += 0x7fffu + ((u >> 16) & 1u);   // round-to-nearest-even
  return (unsigned short)(u >> 16);
}

__device__ inline float bf2f(unsigned short b) {
  return __uint_as_float(((unsigned)b) << 16);
}

// mini-barrier among the PREP block group (co-resident under coop launch)
__device__ inline void prep_bar(int* bar, int idx, int target) {
  __syncthreads();
  if (threadIdx.x == 0) {
    __threadfence();  // release prior writes to device scope
    __hip_atomic_fetch_add(&bar[idx], 1, __ATOMIC_ACQ_REL, __HIP_MEMORY_SCOPE_AGENT);
    while (__hip_atomic_load(&bar[idx], __ATOMIC_ACQUIRE, __HIP_MEMORY_SCOPE_AGENT) < target)
      __builtin_amdgcn_s_sleep(16);
  }
  __syncthreads();
  __threadfence();   // acquire: invalidate L1 before reading others' data
}

// ===========================================================================
// MEGA KERNEL (cooperative): whole network in one dispatch.
// P0 init | P1 prep-chain (PREP blocks) ∥ GEMM1 (rest) | P2 agg1 | P3 GEMM2
// | P4 agg2+gemm3 | P5 agg3+lsm
// ===========================================================================
__global__ __launch_bounds__(256, 4) void k_mega(
    const float* __restrict__ x, const int* __restrict__ ei,
    const float* __restrict__ b1, const float* __restrict__ b2,
    const float* __restrict__ W3, const float* __restrict__ b3,
    float* __restrict__ out,
    int* __restrict__ deg, int* __restrict__ off, int* __restrict__ cur,
    float* __restrict__ dinv, int* __restrict__ bsum, int* __restrict__ bar,
    int* __restrict__ srcs, float* __restrict__ wgt,
    const float* __restrict__ W1, const float* __restrict__ W2,
    unsigned short* __restrict__ W1T, unsigned short* __restrict__ W2T,
    unsigned short* __restrict__ bufHb, unsigned short* __restrict__ bufA,
    float* __restrict__ h3,
    int E, unsigned dk10, unsigned dk11, unsigned dk20, unsigned dk21) {
  cg::grid_group grid = cg::this_grid();
  const int N = 20000;
  const int S1 = 512 * 256, S2 = 256 * 128;
  const int G = gridDim.x;
  const int tid = threadIdx.x;
  const int bid = blockIdx.x;
  const int lane = tid & 63;

  __shared__ unsigned short As[32][40];
  __shared__ unsigned short Bs[256][40];
  __shared__ int smi[4];

  // ---------------- P0: zero deg/bar + weight transpose-convert -------------
  for (int idx = bid * 256 + tid; idx < N + S1 + S2; idx += G * 256) {
    int i = idx;
    if (i < N) { deg[i] = 0; continue; }
    i -= N;
    if (i < S1) { int k = i / 256, c = i % 256; W1T[(size_t)c * 512 + k] = f2bf(W1[i]); continue; }
    i -= S1;
    { int k = i / 128, c = i % 128; W2T[(size_t)c * 256 + k] = f2bf(W2[i]); }
  }
  if (bid == 0 && tid < 16) bar[tid] = 0;
  grid.sync();

  // ---------------- P1: prep chain (PREP blocks)  ∥  GEMM1 (rest) ----------
  const int PREP = G / 4;
  if (bid < PREP) {
    // deg
    for (int e = bid * 256 + tid; e < E; e += PREP * 256)
      atomicAdd(&deg[ei[E + e]], 1);
    prep_bar(bar, 0, PREP);
    // bsum over 256-node chunks
    const int NB = (N + 255) / 256;
    for (int c = bid; c < NB; c += PREP) {
      int i = c * 256 + tid;
      int v = (i < N) ? deg[i] : 0;
#pragma unroll
      for (int o = 32; o; o >>= 1) v += __shfl_down(v, o);
      if ((tid & 63) == 0) smi[tid >> 6] = v;
      __syncthreads();
      if (tid == 0) bsum[c] = smi[0] + smi[1] + smi[2] + smi[3];
      __syncthreads();
    }
    prep_bar(bar, 1, PREP);
    // scatter: off/cur/dinv
    for (int c = bid; c < NB; c += PREP) {
      int i = c * 256 + tid;
      int w = tid >> 6;
      int pb = 0;
      for (int k = lane; k < c; k += 64) pb += bsum[k];
#pragma unroll
      for (int o = 32; o; o >>= 1) pb += __shfl_xor(pb, o);
      int d = (i < N) ? deg[i] : 0;
      int inc = d;
#pragma unroll
      for (int o = 1; o < 64; o <<= 1) {
        int u = __shfl_up(inc, o);
        if (lane >= o) inc += u;
      }
      if (lane == 63) smi[w] = inc;
      __syncthreads();
      int wbase = 0;
      for (int k = 0; k < w; ++k) wbase += smi[k];
      int excl = inc - d + wbase + pb;
      if (i < N) {
        off[i] = excl;
        cur[i] = excl;
        dinv[i] = 1.0f / sqrtf((float)(d + 1));
        if (i == N - 1) off[N] = excl + d;
      }
      __syncthreads();
    }
    prep_bar(bar, 2, PREP);
    // fill srcs + wgt
    for (int e = bid * 256 + tid; e < E; e += PREP * 256) {
      int s = ei[e];
      int d = ei[E + e];
      int pos = atomicAdd(&cur[d], 1);
      srcs[pos] = s;
      wgt[pos] = dinv[s] * dinv[d];
    }
  } else {
    // GEMM1: h1(bf16)[N,256] = x[N,512] @ W1 ; BN=256, 4 waves x (32x64)
    const int wn = tid >> 6;
    const int lr = lane & 15, lk = lane >> 4;
    const int ar = tid >> 3, aseg = (tid & 7) * 4;
    for (int t = bid - PREP; t < N / 32; t += G - PREP) {
      const int row0 = t * 32;
      f32x4 acc[2][4];
#pragma unroll
      for (int mi = 0; mi < 2; ++mi)
#pragma unroll
        for (int ni = 0; ni < 4; ++ni) acc[mi][ni] = (f32x4)0.0f;
      for (int k0 = 0; k0 < 512; k0 += 32) {
        {
          float4 v = *(const float4*)&x[(size_t)(row0 + ar) * 512 + k0 + aseg];
          unsigned short a4[4] = {f2bf(v.x), f2bf(v.y), f2bf(v.z), f2bf(v.w)};
          *(ushort4v*)&As[ar][aseg] = *(ushort4v*)a4;
        }
#pragma unroll
        for (int p = 0; p < 4; ++p) {
          int u = tid + p * 256;
          int br = u >> 2, bseg = (u & 3) * 8;
          *(ushort8*)&Bs[br][bseg] = *(const ushort8*)&W1T[(size_t)br * 512 + k0 + bseg];
        }
        __syncthreads();
        short8 a[2], b[4];
#pragma unroll
        for (int mi = 0; mi < 2; ++mi) a[mi] = *(const short8*)&As[mi * 16 + lr][lk * 8];
#pragma unroll
        for (int ni = 0; ni < 4; ++ni) b[ni] = *(const short8*)&Bs[wn * 64 + ni * 16 + lr][lk * 8];
#pragma unroll
        for (int mi = 0; mi < 2; ++mi)
#pragma unroll
          for (int ni = 0; ni < 4; ++ni)
            acc[mi][ni] = __builtin_amdgcn_mfma_f32_16x16x32_bf16(a[mi], b[ni], acc[mi][ni], 0, 0, 0);
        __syncthreads();
      }
#pragma unroll
      for (int mi = 0; mi < 2; ++mi) {
        int rbase = row0 + mi * 16 + lk * 4;
#pragma unroll
        for (int j = 0; j < 4; ++j)
#pragma unroll
          for (int ni = 0; ni < 4; ++ni) {
            int col = wn * 64 + ni * 16 + lr;
            bufHb[(size_t)(rbase + j) * 256 + col] = f2bf(acc[mi][ni][j]);
          }
      }
    }
  }
  grid.sync();

  // ---------------- P2: agg1 (h1 -> a1 bf16, bias+relu+dropout dk1) --------
  for (int u0 = bid; u0 < N / 4; u0 += G) {
    const int node = u0 * 4 + (tid >> 6);
    const float dv = dinv[node];
    float acc[4];
    {
      ushort4v r = *(const ushort4v*)(bufHb + (size_t)node * 256 + lane * 4);
      float wv = dv * dv;
#pragma unroll
      for (int j = 0; j < 4; ++j) acc[j] = bf2f(r[j]) * wv;
    }
    int e = off[node];
    const int e1 = off[node + 1];
    for (; e + 8 <= e1; e += 8) {
      int s[8]; float wv[8]; ushort4v r[8];
#pragma unroll
      for (int q = 0; q < 8; ++q) s[q] = srcs[e + q];
#pragma unroll
      for (int q = 0; q < 8; ++q) wv[q] = wgt[e + q];
#pragma unroll
      for (int q = 0; q < 8; ++q) r[q] = *(const ushort4v*)(bufHb + (size_t)s[q] * 256 + lane * 4);
#pragma unroll
      for (int q = 0; q < 8; ++q)
#pragma unroll
        for (int j = 0; j < 4; ++j) acc[j] += bf2f(r[q][j]) * wv[q];
    }
    for (; e < e1; ++e) {
      int s = srcs[e];
      float wv = wgt[e];
      ushort4v r = *(const ushort4v*)(bufHb + (size_t)s * 256 + lane * 4);
#pragma unroll
      for (int j = 0; j < 4; ++j) acc[j] += bf2f(r[j]) * wv;
    }
    unsigned short o4[4];
#pragma unroll
    for (int j = 0; j < 4; ++j) {
      float v = fmaxf(acc[j] + b1[lane * 4 + j], 0.0f);
      float u = jax_uniform01(dk10, dk11, (unsigned)(node * 256 + lane * 4 + j));
      o4[j] = f2bf((u < 0.8f) ? (v * 1.25f) : 0.0f);
    }
    *(ushort4v*)(bufA + (size_t)node * 256 + lane * 4) = *(ushort4v*)o4;
  }
  grid.sync();

  // ---------------- P3: GEMM2  h2(bf16)[N,128] = a1 @ W2 -------------------
  {
    const int wn = tid >> 6;
    const int lr = lane & 15, lk = lane >> 4;
    const int ar = tid >> 3, aseg = (tid & 7) * 4;
    for (int t = bid; t < N / 32; t += G) {
      const int row0 = t * 32;
      f32x4 acc[2][2];
#pragma unroll
      for (int mi = 0; mi < 2; ++mi)
#pragma unroll
        for (int ni = 0; ni < 2; ++ni) acc[mi][ni] = (f32x4)0.0f;
      for (int k0 = 0; k0 < 256; k0 += 32) {
        *(ushort4v*)&As[ar][aseg] =
            *(const ushort4v*)&bufA[(size_t)(row0 + ar) * 256 + k0 + aseg];
#pragma unroll
        for (int p = 0; p < 2; ++p) {
          int u = tid + p * 256;
          int br = u >> 2, bseg = (u & 3) * 8;
          *(ushort8*)&Bs[br][bseg] = *(const ushort8*)&W2T[(size_t)br * 256 + k0 + bseg];
        }
        __syncthreads();
        short8 a[2], b[2];
#pragma unroll
        for (int mi = 0; mi < 2; ++mi) a[mi] = *(const short8*)&As[mi * 16 + lr][lk * 8];
#pragma unroll
        for (int ni = 0; ni < 2; ++ni) b[ni] = *(const short8*)&Bs[wn * 32 + ni * 16 + lr][lk * 8];
#pragma unroll
        for (int mi = 0; mi < 2; ++mi)
#pragma unroll
          for (int ni = 0; ni < 2; ++ni)
            acc[mi][ni] = __builtin_amdgcn_mfma_f32_16x16x32_bf16(a[mi], b[ni], acc[mi][ni], 0, 0, 0);
        __syncthreads();
      }
#pragma unroll
      for (int mi = 0; mi < 2; ++mi) {
        int rbase = row0 + mi * 16 + lk * 4;
#pragma unroll
        for (int j = 0; j < 4; ++j)
#pragma unroll
          for (int ni = 0; ni < 2; ++ni) {
            int col = wn * 32 + ni * 16 + lr;
            bufHb[(size_t)(rbase + j) * 128 + col] = f2bf(acc[mi][ni][j]);
          }
      }
    }
  }
  grid.sync();

  // ---------------- P4: agg2 + bias/relu/dropout(dk2) + GEMM3 -> h3 --------
  for (int u0 = bid; u0 < N / 4; u0 += G) {
    const int node = u0 * 4 + (tid >> 6);
    float w3a[10], w3b[10];
    {
      const float4* p = (const float4*)(W3 + lane * 20);
      float4 v0 = p[0], v1 = p[1], v2 = p[2], v3 = p[3], v4 = p[4];
      w3a[0] = v0.x; w3a[1] = v0.y; w3a[2] = v0.z; w3a[3] = v0.w;
      w3a[4] = v1.x; w3a[5] = v1.y; w3a[6] = v1.z; w3a[7] = v1.w;
      w3a[8] = v2.x; w3a[9] = v2.y;
      w3b[0] = v2.z; w3b[1] = v2.w;
      w3b[2] = v3.x; w3b[3] = v3.y; w3b[4] = v3.z; w3b[5] = v3.w;
      w3b[6] = v4.x; w3b[7] = v4.y; w3b[8] = v4.z; w3b[9] = v4.w;
    }
    const float dv = dinv[node];
    float acc0, acc1;
    {
      unsigned r = *(const unsigned*)(bufHb + (size_t)node * 128 + lane * 2);
      float wv = dv * dv;
      acc0 = bf2f((unsigned short)(r & 0xffffu)) * wv;
      acc1 = bf2f((unsigned short)(r >> 16)) * wv;
    }
    int e = off[node];
    const int e1 = off[node + 1];
    for (; e + 8 <= e1; e += 8) {
      int s[8]; float wv[8]; unsigned r[8];
#pragma unroll
      for (int q = 0; q < 8; ++q) s[q] = srcs[e + q];
#pragma unroll
      for (int q = 0; q < 8; ++q) wv[q] = wgt[e + q];
#pragma unroll
      for (int q = 0; q < 8; ++q) r[q] = *(const unsigned*)(bufHb + (size_t)s[q] * 128 + lane * 2);
#pragma unroll
      for (int q = 0; q < 8; ++q) {
        acc0 += bf2f((unsigned short)(r[q] & 0xffffu)) * wv[q];
        acc1 += bf2f((unsigned short)(r[q] >> 16)) * wv[q];
      }
    }
    for (; e < e1; ++e) {
      int s = srcs[e];
      float wv = wgt[e];
      unsigned r = *(const unsigned*)(bufHb + (size_t)s * 128 + lane * 2);
      acc0 += bf2f((unsigned short)(r & 0xffffu)) * wv;
      acc1 += bf2f((unsigned short)(r >> 16)) * wv;
    }
    {
      float v = fmaxf(acc0 + b2[lane * 2], 0.0f);
      float u = jax_uniform01(dk20, dk21, (unsigned)(node * 128 + lane * 2));
      acc0 = (u < 0.8f) ? (v * 1.25f) : 0.0f;
    }
    {
      float v = fmaxf(acc1 + b2[lane * 2 + 1], 0.0f);
      float u = jax_uniform01(dk20, dk21, (unsigned)(node * 128 + lane * 2 + 1));
      acc1 = (u < 0.8f) ? (v * 1.25f) : 0.0f;
    }
    float myout = 0.0f;
#pragma unroll
    for (int c = 0; c < 10; ++c) {
      float part = acc0 * w3a[c] + acc1 * w3b[c];
#pragma unroll
      for (int o = 32; o; o >>= 1) part += __shfl_xor(part, o);
      if (lane == c) myout = part;
    }
    if (lane < 10) h3[(size_t)node * 10 + lane] = myout;
  }
  grid.sync();

  // ---------------- P5: agg3 + bias + log_softmax -> out -------------------
  for (int u0 = bid; u0 < N / 4; u0 += G) {
    const int node = u0 * 4 + (tid >> 6);
    const bool act = (lane < 10);
    const float dv = dinv[node];
    float acc = 0.0f;
    if (act) acc = h3[(size_t)node * 10 + lane] * dv * dv;
    int e = off[node];
    const int e1 = off[node + 1];
    for (; e + 4 <= e1; e += 4) {
      int s0 = srcs[e + 0], s1 = srcs[e + 1], s2 = srcs[e + 2], s3 = srcs[e + 3];
      float w0 = wgt[e + 0], w1 = wgt[e + 1], w2 = wgt[e + 2], w3 = wgt[e + 3];
      if (act) {
        acc += h3[(size_t)s0 * 10 + lane] * w0 + h3[(size_t)s1 * 10 + lane] * w1 +
               h3[(size_t)s2 * 10 + lane] * w2 + h3[(size_t)s3 * 10 + lane] * w3;
      }
    }
    for (; e < e1; ++e) {
      int s = srcs[e];
      float w = wgt[e];
      if (act) acc += h3[(size_t)s * 10 + lane] * w;
    }
    float v = act ? (acc + b3[lane]) : -1e30f;
    float m = v;
#pragma unroll
    for (int o = 32; o; o >>= 1) m = fmaxf(m, __shfl_xor(m, o));
    float p = act ? expf(v - m) : 0.0f;
    float ssum = p;
#pragma unroll
    for (int o = 32; o; o >>= 1) ssum += __shfl_xor(ssum, o);
    float lse = m + logf(ssum);
    if (act) out[(size_t)node * 10 + lane] = v - lse;
  }
}

// ===========================================================================
// FALLBACK PATH (R7 kernels, verbatim) — used if cooperative launch fails.
// ===========================================================================
__global__ __launch_bounds__(256) void k_init(int* __restrict__ deg, int n,
                                              const float* __restrict__ W1,
                                              unsigned short* __restrict__ W1T,
                                              const float* __restrict__ W2,
                                              unsigned short* __restrict__ W2T) {
  const int S1 = 512 * 256, S2 = 256 * 128;
  int idx = blockIdx.x * 256 + threadIdx.x;
  if (idx < n) { deg[idx] = 0; return; }
  idx -= n;
  if (idx < S1) {
    int k = idx / 256, c = idx % 256;
    W1T[(size_t)c * 512 + k] = f2bf(W1[idx]);
    return;
  }
  idx -= S1;
  if (idx < S2) {
    int k = idx / 128, c = idx % 128;
    W2T[(size_t)c * 256 + k] = f2bf(W2[idx]);
  }
}

__global__ void k_deg(const int* __restrict__ ei, int E, int* __restrict__ deg) {
  int e = blockIdx.x * blockDim.x + threadIdx.x;
  if (e >= E) return;
  atomicAdd(&deg[ei[E + e]], 1);
}

__global__ __launch_bounds__(256) void k_bsum(const int* __restrict__ deg,
                                              int* __restrict__ bsum, int n) {
  int i = blockIdx.x * 256 + threadIdx.x;
  int v = (i < n) ? deg[i] : 0;
#pragma unroll
  for (int o = 32; o; o >>= 1) v += __shfl_down(v, o);
  __shared__ int ws[4];
  if ((threadIdx.x & 63) == 0) ws[threadIdx.x >> 6] = v;
  __syncthreads();
  if (threadIdx.x == 0) bsum[blockIdx.x] = ws[0] + ws[1] + ws[2] + ws[3];
}

__global__ __launch_bounds__(256) void k_scatter2(const int* __restrict__ deg,
                                                  const int* __restrict__ bsum,
                                                  int* __restrict__ off, int* __restrict__ cur,
                                                  float* __restrict__ dinv, int n) {
  int i = blockIdx.x * 256 + threadIdx.x;
  int lane = threadIdx.x & 63, w = threadIdx.x >> 6;
  int pb = 0;
  for (int k = lane; k < blockIdx.x; k += 64) pb += bsum[k];
#pragma unroll
  for (int o = 32; o; o >>= 1) pb += __shfl_xor(pb, o);
  int d = (i < n) ? deg[i] : 0;
  int inc = d;
#pragma unroll
  for (int o = 1; o < 64; o <<= 1) {
    int u = __shfl_up(inc, o);
    if (lane >= o) inc += u;
  }
  __shared__ int wsum[4];
  if (lane == 63) wsum[w] = inc;
  __syncthreads();
  int wbase = 0;
  for (int k = 0; k < w; ++k) wbase += wsum[k];
  int excl = inc - d + wbase + pb;
  if (i < n) {
    off[i] = excl;
    cur[i] = excl;
    dinv[i] = 1.0f / sqrtf((float)(d + 1));
    if (i == n - 1) off[n] = excl + d;
  }
}

__global__ void k_fill_w(const int* __restrict__ ei, int E,
                         int* __restrict__ cur, int* __restrict__ srcs,
                         float* __restrict__ wgt, const float* __restrict__ dinv) {
  int e = blockIdx.x * blockDim.x + threadIdx.x;
  if (e >= E) return;
  int s = ei[e];
  int d = ei[E + e];
  int pos = atomicAdd(&cur[d], 1);
  srcs[pos] = s;
  wgt[pos] = dinv[s] * dinv[d];
}

template <int BN, bool AF32, bool OBF>
__global__ __launch_bounds__(256) void k_gemm_mfma(const void* __restrict__ Ap,
                                                   const unsigned short* __restrict__ BT,
                                                   void* __restrict__ Cp,
                                                   int M, int N, int K) {
  constexpr int WCOLS = BN / 4;
  constexpr int NFW = WCOLS / 16;
  __shared__ unsigned short As[32][40];
  __shared__ unsigned short Bs[BN][40];
  const int tid = threadIdx.x;
  const int row0 = blockIdx.y * 32;
  const int col0 = blockIdx.x * BN;
  const int wn = tid >> 6, lane = tid & 63;
  const int lr = lane & 15, lk = lane >> 4;
  f32x4 acc[2][NFW];
#pragma unroll
  for (int mi = 0; mi < 2; ++mi)
#pragma unroll
    for (int ni = 0; ni < NFW; ++ni) acc[mi][ni] = (f32x4)0.0f;
  const int ar = tid >> 3;
  const int aseg = (tid & 7) * 4;
  for (int k0 = 0; k0 < K; k0 += 32) {
    {
      int grow = row0 + ar;
      unsigned short a4[4] = {0, 0, 0, 0};
      if (grow < M) {
        if (AF32) {
          const float* A = (const float*)Ap;
          float4 v = *(const float4*)&A[(size_t)grow * K + k0 + aseg];
          a4[0] = f2bf(v.x); a4[1] = f2bf(v.y); a4[2] = f2bf(v.z); a4[3] = f2bf(v.w);
        } else {
          const unsigned short* A = (const unsigned short*)Ap;
          ushort4v v = *(const ushort4v*)&A[(size_t)grow * K + k0 + aseg];
          a4[0] = v[0]; a4[1] = v[1]; a4[2] = v[2]; a4[3] = v[3];
        }
      }
      *(ushort4v*)&As[ar][aseg] = *(ushort4v*)a4;
    }
#pragma unroll
    for (int p = 0; p < BN / 64; ++p) {
      int u = tid + p * 256;
      int br = u >> 2;
      int bseg = (u & 3) * 8;
      ushort8 bv = *(const ushort8*)&BT[(size_t)(col0 + br) * K + k0 + bseg];
      *(ushort8*)&Bs[br][bseg] = bv;
    }
    __syncthreads();
    short8 a[2], b[NFW];
#pragma unroll
    for (int mi = 0; mi < 2; ++mi)
      a[mi] = *(const short8*)&As[mi * 16 + lr][lk * 8];
#pragma unroll
    for (int ni = 0; ni < NFW; ++ni)
      b[ni] = *(const short8*)&Bs[wn * WCOLS + ni * 16 + lr][lk * 8];
#pragma unroll
    for (int mi = 0; mi < 2; ++mi)
#pragma unroll
      for (int ni = 0; ni < NFW; ++ni)
        acc[mi][ni] = __builtin_amdgcn_mfma_f32_16x16x32_bf16(a[mi], b[ni], acc[mi][ni], 0, 0, 0);
    __syncthreads();
  }
#pragma unroll
  for (int mi = 0; mi < 2; ++mi) {
    int rbase = row0 + mi * 16 + lk * 4;
#pragma unroll
    for (int j = 0; j < 4; ++j) {
      int row = rbase + j;
      if (row < M) {
#pragma unroll
        for (int ni = 0; ni < NFW; ++ni) {
          int col = col0 + wn * WCOLS + ni * 16 + lr;
          if (OBF) ((unsigned short*)Cp)[(size_t)row * N + col] = f2bf(acc[mi][ni][j]);
          else ((float*)Cp)[(size_t)row * N + col] = acc[mi][ni][j];
        }
      }
    }
  }
}

template <int C, bool OBF>
__global__ __launch_bounds__(256) void k_agg_bf(const unsigned short* __restrict__ h,
                                                void* __restrict__ outv,
                                                const int* __restrict__ off,
                                                const int* __restrict__ srcs,
                                                const float* __restrict__ wgt,
                                                const float* __restrict__ dinv,
                                                const float* __restrict__ bias,
                                                unsigned key0, unsigned key1, int n) {
  typedef __attribute__((ext_vector_type(C))) unsigned short ushortC;
  const int node = blockIdx.x * (blockDim.x >> 6) + (threadIdx.x >> 6);
  if (node >= n) return;
  const int lane = threadIdx.x & 63;
  const int F = 64 * C;
  const float dv = dinv[node];
  float acc[C];
  {
    ushortC r = *(const ushortC*)(h + (size_t)node * F + lane * C);
    float wv = dv * dv;
#pragma unroll
    for (int j = 0; j < C; ++j) acc[j] = bf2f(r[j]) * wv;
  }
  int e = off[node];
  const int e1 = off[node + 1];
  for (; e + 8 <= e1; e += 8) {
    int s[8]; float wv[8]; ushortC r[8];
#pragma unroll
    for (int q = 0; q < 8; ++q) s[q] = srcs[e + q];
#pragma unroll
    for (int q = 0; q < 8; ++q) wv[q] = wgt[e + q];
#pragma unroll
    for (int q = 0; q < 8; ++q) r[q] = *(const ushortC*)(h + (size_t)s[q] * F + lane * C);
#pragma unroll
    for (int q = 0; q < 8; ++q)
#pragma unroll
      for (int j = 0; j < C; ++j) acc[j] += bf2f(r[q][j]) * wv[q];
  }
  for (; e < e1; ++e) {
    int s = srcs[e];
    float wv = wgt[e];
    ushortC r = *(const ushortC*)(h + (size_t)s * F + lane * C);
#pragma unroll
    for (int j = 0; j < C; ++j) acc[j] += bf2f(r[j]) * wv;
  }
#pragma unroll
  for (int j = 0; j < C; ++j) {
    float v = acc[j] + bias[lane * C + j];
    v = fmaxf(v, 0.0f);
    unsigned i = (unsigned)(node * F + lane * C + j);
    float u = jax_uniform01(key0, key1, i);
    v = (u < 0.8f) ? (v * 1.25f) : 0.0f;
    acc[j] = v;
  }
  if (OBF) {
    unsigned short* op = (unsigned short*)outv + (size_t)node * F + lane * C;
#pragma unroll
    for (int j = 0; j < C; ++j) op[j] = f2bf(acc[j]);
  } else {
    float* op = (float*)outv + (size_t)node * F + lane * C;
#pragma unroll
    for (int j = 0; j < C; ++j) op[j] = acc[j];
  }
}

__global__ __launch_bounds__(256) void k_agg2_g3(const unsigned short* __restrict__ h,
                                                 float* __restrict__ h3,
                                                 const int* __restrict__ off,
                                                 const int* __restrict__ srcs,
                                                 const float* __restrict__ wgt,
                                                 const float* __restrict__ dinv,
                                                 const float* __restrict__ b2,
                                                 const float* __restrict__ W3,
                                                 unsigned key0, unsigned key1, int n) {
  const int node = blockIdx.x * 4 + (threadIdx.x >> 6);
  if (node >= n) return;
  const int lane = threadIdx.x & 63;
  float w3a[10], w3b[10];
  {
    const float4* p = (const float4*)(W3 + lane * 20);
    float4 v0 = p[0], v1 = p[1], v2 = p[2], v3 = p[3], v4 = p[4];
    w3a[0] = v0.x; w3a[1] = v0.y; w3a[2] = v0.z; w3a[3] = v0.w;
    w3a[4] = v1.x; w3a[5] = v1.y; w3a[6] = v1.z; w3a[7] = v1.w;
    w3a[8] = v2.x; w3a[9] = v2.y;
    w3b[0] = v2.z; w3b[1] = v2.w;
    w3b[2] = v3.x; w3b[3] = v3.y; w3b[4] = v3.z; w3b[5] = v3.w;
    w3b[6] = v4.x; w3b[7] = v4.y; w3b[8] = v4.z; w3b[9] = v4.w;
  }
  const float dv = dinv[node];
  float acc0, acc1;
  {
    unsigned r = *(const unsigned*)(h + (size_t)node * 128 + lane * 2);
    float wv = dv * dv;
    acc0 = bf2f((unsigned short)(r & 0xffffu)) * wv;
    acc1 = bf2f((unsigned short)(r >> 16)) * wv;
  }
  int e = off[node];
  const int e1 = off[node + 1];
  for (; e + 8 <= e1; e += 8) {
    int s[8]; float wv[8]; unsigned r[8];
#pragma unroll
    for (int q = 0; q < 8; ++q) s[q] = srcs[e + q];
#pragma unroll
    for (int q = 0; q < 8; ++q) wv[q] = wgt[e + q];
#pragma unroll
    for (int q = 0; q < 8; ++q) r[q] = *(const unsigned*)(h + (size_t)s[q] * 128 + lane * 2);
#pragma unroll
    for (int q = 0; q < 8; ++q) {
      acc0 += bf2f((unsigned short)(r[q] & 0xffffu)) * wv[q];
      acc1 += bf2f((unsigned short)(r[q] >> 16)) * wv[q];
    }
  }
  for (; e < e1; ++e) {
    int s = srcs[e];
    float wv = wgt[e];
    unsigned r = *(const unsigned*)(h + (size_t)s * 128 + lane * 2);
    acc0 += bf2f((unsigned short)(r & 0xffffu)) * wv;
    acc1 += bf2f((unsigned short)(r >> 16)) * wv;
  }
  {
    float v = fmaxf(acc0 + b2[lane * 2], 0.0f);
    float u = jax_uniform01(key0, key1, (unsigned)(node * 128 + lane * 2));
    acc0 = (u < 0.8f) ? (v * 1.25f) : 0.0f;
  }
  {
    float v = fmaxf(acc1 + b2[lane * 2 + 1], 0.0f);
    float u = jax_uniform01(key0, key1, (unsigned)(node * 128 + lane * 2 + 1));
    acc1 = (u < 0.8f) ? (v * 1.25f) : 0.0f;
  }
  float myout = 0.0f;
#pragma unroll
  for (int c = 0; c < 10; ++c) {
    float part = acc0 * w3a[c] + acc1 * w3b[c];
#pragma unroll
    for (int o = 32; o; o >>= 1) part += __shfl_xor(part, o);
    if (lane == c) myout = part;
  }
  if (lane < 10) h3[(size_t)node * 10 + lane] = myout;
}

__global__ __launch_bounds__(256) void k_agg3_lsm_v2(const float* __restrict__ h,
                                                     float* __restrict__ out,
                                                     const int* __restrict__ off,
                                                     const int* __restrict__ srcs,
                                                     const float* __restrict__ wgt,
                                                     const float* __restrict__ dinv,
                                                     const float* __restrict__ b,
                                                     int n) {
  const int node = blockIdx.x * 4 + (threadIdx.x >> 6);
  if (node >= n) return;
  const int lane = threadIdx.x & 63;
  const bool act = (lane < 10);
  const float dv = dinv[node];
  float acc = 0.0f;
  if (act) acc = h[(size_t)node * 10 + lane] * dv * dv;
  int e = off[node];
  const int e1 = off[node + 1];
  for (; e + 4 <= e1; e += 4) {
    int s0 = srcs[e + 0], s1 = srcs[e + 1], s2 = srcs[e + 2], s3 = srcs[e + 3];
    float w0 = wgt[e + 0], w1 = wgt[e + 1], w2 = wgt[e + 2], w3 = wgt[e + 3];
    if (act) {
      acc += h[(size_t)s0 * 10 + lane] * w0 + h[(size_t)s1 * 10 + lane] * w1 +
             h[(size_t)s2 * 10 + lane] * w2 + h[(size_t)s3 * 10 + lane] * w3;
    }
  }
  for (; e < e1; ++e) {
    int s = srcs[e];
    float w = wgt[e];
    if (act) acc += h[(size_t)s * 10 + lane] * w;
  }
  float v = act ? (acc + b[lane]) : -1e30f;
  float m = v;
#pragma unroll
  for (int o = 32; o; o >>= 1) m = fmaxf(m, __shfl_xor(m, o));
  float p = act ? expf(v - m) : 0.0f;
  float ssum = p;
#pragma unroll
  for (int o = 32; o; o >>= 1) ssum += __shfl_xor(ssum, o);
  float lse = m + logf(ssum);
  if (act) out[(size_t)node * 10 + lane] = v - lse;
}

// ---------------------------------------------------------------------------
extern "C" void kernel_launch(void* const* d_in, const int* in_sizes, int n_in,
                              void* d_out, int out_size, void* d_ws, size_t ws_size,
                              hipStream_t stream) {
  const float* x  = (const float*)d_in[0];
  const int*   ei = (const int*)d_in[1];
  const float* W1 = (const float*)d_in[2];
  const float* b1 = (const float*)d_in[3];
  const float* W2 = (const float*)d_in[4];
  const float* b2 = (const float*)d_in[5];
  const float* W3 = (const float*)d_in[6];
  const float* b3 = (const float*)d_in[7];
  float* out = (float*)d_out;

  const int N = 20000;
  int E = in_sizes[1] / 2;
  const int D1 = 256, D2 = 128;
  const int NB = (N + 255) / 256;

  char* ws = (char*)d_ws;
  auto carve = [&](size_t bytes) -> char* {
    char* p = ws;
    ws += (bytes + 255) & ~(size_t)255;
    return p;
  };
  int*   deg  = (int*)carve((size_t)N * 4);
  int*   off  = (int*)carve((size_t)(N + 1) * 4);
  int*   cur  = (int*)carve((size_t)N * 4);
  float* dinv = (float*)carve((size_t)N * 4);
  int*   bsum = (int*)carve((size_t)128 * 4);
  int*   bar  = (int*)carve((size_t)16 * 4);
  int*   srcs = (int*)carve((size_t)E * 4);
  float* wgt  = (float*)carve((size_t)E * 4);
  unsigned short* W1T = (unsigned short*)carve((size_t)D1 * 512 * 2);
  unsigned short* W2T = (unsigned short*)carve((size_t)D2 * D1 * 2);
  unsigned short* bufHb = (unsigned short*)carve((size_t)N * D1 * 2);
  unsigned short* bufA  = (unsigned short*)carve((size_t)N * D1 * 2);
  float* h3 = (float*)carve((size_t)N * 10 * 4);

  unsigned dk1_0, dk1_1, dk2_0, dk2_1;
  threefry2x32(0u, 1u, 0u, 0u, &dk1_0, &dk1_1);
  threefry2x32(0u, 1u, 0u, 1u, &dk2_0, &dk2_1);

  // -------- try the cooperative mega-kernel at decreasing grid sizes -------
  void* args[] = {(void*)&x, (void*)&ei, (void*)&b1, (void*)&b2, (void*)&W3,
                  (void*)&b3, (void*)&out, (void*)&deg, (void*)&off, (void*)&cur,
                  (void*)&dinv, (void*)&bsum, (void*)&bar, (void*)&srcs,
                  (void*)&wgt, (void*)&W1, (void*)&W2, (void*)&W1T, (void*)&W2T,
                  (void*)&bufHb, (void*)&bufA, (void*)&h3, (void*)&E,
                  (void*)&dk1_0, (void*)&dk1_1, (void*)&dk2_0, (void*)&dk2_1};
  const int grids[3] = {1024, 768, 512};
  for (int gi = 0; gi < 3; ++gi) {
    hipError_t rc = hipLaunchCooperativeKernel((const void*)k_mega, dim3(grids[gi]),
                                               dim3(256), args, 0, stream);
    if (rc == hipSuccess) return;
    (void)hipGetLastError();  // clear error state, try smaller / fallback
  }

  // ------------------------- fallback: R7 path -----------------------------
  const int INIT_ITEMS = N + 512 * 256 + 256 * 128;
  k_init<<<(INIT_ITEMS + 255) / 256, 256, 0, stream>>>(deg, N, W1, W1T, W2, W2T);
  k_deg<<<(E + 255) / 256, 256, 0, stream>>>(ei, E, deg);
  k_bsum<<<NB, 256, 0, stream>>>(deg, bsum, N);
  k_scatter2<<<NB, 256, 0, stream>>>(deg, bsum, off, cur, dinv, N);
  k_fill_w<<<(E + 255) / 256, 256, 0, stream>>>(ei, E, cur, srcs, wgt, dinv);
  k_gemm_mfma<256, true, true><<<dim3(1, N / 32), 256, 0, stream>>>(x, W1T, bufHb, N, D1, 512);
  k_agg_bf<4, true><<<(N + 3) / 4, 256, 0, stream>>>(bufHb, bufA, off, srcs, wgt, dinv, b1, dk1_0, dk1_1, N);
  k_gemm_mfma<128, false, true><<<dim3(1, N / 32), 256, 0, stream>>>(bufA, W2T, bufHb, N, D2, D1);
  k_agg2_g3<<<(N + 3) / 4, 256, 0, stream>>>(bufHb, h3, off, srcs, wgt, dinv, b2, W3, dk2_0, dk2_1, N);
  k_agg3_lsm_v2<<<(N + 3) / 4, 256, 0, stream>>>(h3, out, off, srcs, wgt, dinv, b3, N);
}

// Round 9
// 346.888 us; speedup vs baseline: 2.6288x; 2.6288x over previous
//
#include <hip/hip_runtime.h>
#include <hip/hip_bf16.h>
#include <math.h>

typedef __attribute__((ext_vector_type(8))) short short8;
typedef __attribute__((ext_vector_type(8))) unsigned short ushort8;
typedef __attribute__((ext_vector_type(4))) unsigned short ushort4v;
typedef __attribute__((ext_vector_type(4))) float f32x4;

#define PREPB 128

// ---------------------------------------------------------------------------
// JAX threefry2x32 (20 rounds) — verified bit-exact vs jax.random in R1.
// ---------------------------------------------------------------------------
__host__ __device__ inline void threefry2x32(unsigned k0, unsigned k1,
                                             unsigned x0, unsigned x1,
                                             unsigned* out0, unsigned* out1) {
  unsigned ks0 = k0, ks1 = k1, ks2 = k0 ^ k1 ^ 0x1BD11BDAu;
  x0 += ks0; x1 += ks1;
#define TF_ROUND(r) { x0 += x1; x1 = (x1 << (r)) | (x1 >> (32 - (r))); x1 ^= x0; }
  TF_ROUND(13) TF_ROUND(15) TF_ROUND(26) TF_ROUND(6)
  x0 += ks1; x1 += ks2 + 1u;
  TF_ROUND(17) TF_ROUND(29) TF_ROUND(16) TF_ROUND(24)
  x0 += ks2; x1 += ks0 + 2u;
  TF_ROUND(13) TF_ROUND(15) TF_ROUND(26) TF_ROUND(6)
  x0 += ks0; x1 += ks1 + 3u;
  TF_ROUND(17) TF_ROUND(29) TF_ROUND(16) TF_ROUND(24)
  x0 += ks1; x1 += ks2 + 4u;
  TF_ROUND(13) TF_ROUND(15) TF_ROUND(26) TF_ROUND(6)
  x0 += ks2; x1 += ks0 + 5u;
#undef TF_ROUND
  *out0 = x0; *out1 = x1;
}

__device__ inline float jax_uniform01(unsigned key0, unsigned key1, unsigned i) {
  unsigned o0, o1;
  threefry2x32(key0, key1, 0u, i, &o0, &o1);
  unsigned bits = o0 ^ o1;
  return __uint_as_float((bits >> 9) | 0x3f800000u) - 1.0f;
}

__device__ inline unsigned short f2bf(float f) {
  unsigned u = __float_as_uint(f);
  u += 0x7fffu + ((u >> 16) & 1u);   // round-to-nearest-even
  return (unsigned short)(u >> 16);
}

__device__ inline float bf2f(unsigned short b) {
  return __uint_as_float(((unsigned)b) << 16);
}

// mini-barrier among the PREP block group (first PREPB blocks of the grid;
// co-resident by construction: grid needs only ~3 blocks/CU). Proven in R8.
__device__ inline void prep_bar(int* bar, int idx, int target) {
  __syncthreads();
  if (threadIdx.x == 0) {
    __threadfence();  // release prior writes to device scope
    __hip_atomic_fetch_add(&bar[idx], 1, __ATOMIC_ACQ_REL, __HIP_MEMORY_SCOPE_AGENT);
    while (__hip_atomic_load(&bar[idx], __ATOMIC_ACQUIRE, __HIP_MEMORY_SCOPE_AGENT) < target)
      __builtin_amdgcn_s_sleep(8);
  }
  __syncthreads();
  __threadfence();   // acquire side
}

// ===========================================================================
// k_front: [blocks 0..PREPB-1] prep chain  ∥  [blocks PREPB..PREPB+624] GEMM1
// GEMM1: h1(bf16)[N,256] = x[N,512] @ W1 ; per-block 32-row tile, BN=256.
// GEMM blocks spin on bar[7] (W1T/W2T ready), set by prep after phase P0.
// ===========================================================================
__global__ __launch_bounds__(256) void k_front(
    const float* __restrict__ x, const int* __restrict__ ei,
    int* __restrict__ deg, int* __restrict__ off, int* __restrict__ cur,
    float* __restrict__ dinv, int* __restrict__ bsum, int* __restrict__ bar,
    int* __restrict__ srcs, float* __restrict__ wgt,
    const float* __restrict__ W1, const float* __restrict__ W2,
    unsigned short* __restrict__ W1T, unsigned short* __restrict__ W2T,
    unsigned short* __restrict__ h1, int E) {
  const int N = 20000;
  const int S1 = 512 * 256, S2 = 256 * 128;
  const int NB = (N + 255) / 256;
  const int tid = threadIdx.x;
  const int bid = blockIdx.x;
  const int lane = tid & 63;

  __shared__ unsigned short As[32][40];
  __shared__ unsigned short Bs[256][40];
  __shared__ int smi[4];

  if (bid < PREPB) {
    // ---- P0: zero deg + convert W1->W1T, W2->W2T (bf16, transposed) ----
    for (int idx = bid * 256 + tid; idx < N + S1 + S2; idx += PREPB * 256) {
      int i = idx;
      if (i < N) { deg[i] = 0; continue; }
      i -= N;
      if (i < S1) { int k = i / 256, c = i % 256; W1T[(size_t)c * 512 + k] = f2bf(W1[i]); continue; }
      i -= S1;
      { int k = i / 128, c = i % 128; W2T[(size_t)c * 256 + k] = f2bf(W2[i]); }
    }
    prep_bar(bar, 0, PREPB);
    if (bid == 0 && tid == 0)
      __hip_atomic_store(&bar[7], 1, __ATOMIC_RELEASE, __HIP_MEMORY_SCOPE_AGENT);
    // ---- P1: degree histogram ----
    for (int e = bid * 256 + tid; e < E; e += PREPB * 256)
      atomicAdd(&deg[ei[E + e]], 1);
    prep_bar(bar, 1, PREPB);
    // ---- P2: per-256-chunk sums ----
    for (int c = bid; c < NB; c += PREPB) {
      int i = c * 256 + tid;
      int v = (i < N) ? deg[i] : 0;
#pragma unroll
      for (int o = 32; o; o >>= 1) v += __shfl_down(v, o);
      if ((tid & 63) == 0) smi[tid >> 6] = v;
      __syncthreads();
      if (tid == 0) bsum[c] = smi[0] + smi[1] + smi[2] + smi[3];
      __syncthreads();
    }
    prep_bar(bar, 2, PREPB);
    // ---- P3: scatter off/cur/dinv (prefix via redundant bsum reduce) ----
    for (int c = bid; c < NB; c += PREPB) {
      int i = c * 256 + tid;
      int w = tid >> 6;
      int pb = 0;
      for (int k = lane; k < c; k += 64) pb += bsum[k];
#pragma unroll
      for (int o = 32; o; o >>= 1) pb += __shfl_xor(pb, o);
      int d = (i < N) ? deg[i] : 0;
      int inc = d;
#pragma unroll
      for (int o = 1; o < 64; o <<= 1) {
        int u = __shfl_up(inc, o);
        if (lane >= o) inc += u;
      }
      if (lane == 63) smi[w] = inc;
      __syncthreads();
      int wbase = 0;
      for (int k = 0; k < w; ++k) wbase += smi[k];
      int excl = inc - d + wbase + pb;
      if (i < N) {
        off[i] = excl;
        cur[i] = excl;
        dinv[i] = 1.0f / sqrtf((float)(d + 1));
        if (i == N - 1) off[N] = excl + d;
      }
      __syncthreads();
    }
    prep_bar(bar, 3, PREPB);
    // ---- P4: fill srcs + per-edge weight ----
    for (int e = bid * 256 + tid; e < E; e += PREPB * 256) {
      int s = ei[e];
      int d = ei[E + e];
      int pos = atomicAdd(&cur[d], 1);
      srcs[pos] = s;
      wgt[pos] = dinv[s] * dinv[d];
    }
  } else {
    // ---- wait for W1T ready, then one GEMM1 tile ----
    if (tid == 0) {
      while (__hip_atomic_load(&bar[7], __ATOMIC_ACQUIRE, __HIP_MEMORY_SCOPE_AGENT) == 0)
        __builtin_amdgcn_s_sleep(8);
    }
    __syncthreads();
    __threadfence();

    const int t = bid - PREPB;          // 0..624
    const int row0 = t * 32;
    const int wn = tid >> 6;
    const int lr = lane & 15, lk = lane >> 4;
    const int ar = tid >> 3, aseg = (tid & 7) * 4;

    f32x4 acc[2][4];
#pragma unroll
    for (int mi = 0; mi < 2; ++mi)
#pragma unroll
      for (int ni = 0; ni < 4; ++ni) acc[mi][ni] = (f32x4)0.0f;

    for (int k0 = 0; k0 < 512; k0 += 32) {
      {
        float4 v = *(const float4*)&x[(size_t)(row0 + ar) * 512 + k0 + aseg];
        unsigned short a4[4] = {f2bf(v.x), f2bf(v.y), f2bf(v.z), f2bf(v.w)};
        *(ushort4v*)&As[ar][aseg] = *(ushort4v*)a4;
      }
#pragma unroll
      for (int p = 0; p < 4; ++p) {
        int u = tid + p * 256;
        int br = u >> 2, bseg = (u & 3) * 8;
        *(ushort8*)&Bs[br][bseg] = *(const ushort8*)&W1T[(size_t)br * 512 + k0 + bseg];
      }
      __syncthreads();
      short8 a[2], b[4];
#pragma unroll
      for (int mi = 0; mi < 2; ++mi) a[mi] = *(const short8*)&As[mi * 16 + lr][lk * 8];
#pragma unroll
      for (int ni = 0; ni < 4; ++ni) b[ni] = *(const short8*)&Bs[wn * 64 + ni * 16 + lr][lk * 8];
#pragma unroll
      for (int mi = 0; mi < 2; ++mi)
#pragma unroll
        for (int ni = 0; ni < 4; ++ni)
          acc[mi][ni] = __builtin_amdgcn_mfma_f32_16x16x32_bf16(a[mi], b[ni], acc[mi][ni], 0, 0, 0);
      __syncthreads();
    }
    // epilogue: C/D layout col=lane&15, row=(lane>>4)*4+reg  [m89-verified]
#pragma unroll
    for (int mi = 0; mi < 2; ++mi) {
      int rbase = row0 + mi * 16 + lk * 4;
#pragma unroll
      for (int j = 0; j < 4; ++j)
#pragma unroll
        for (int ni = 0; ni < 4; ++ni) {
          int col = wn * 64 + ni * 16 + lr;
          h1[(size_t)(rbase + j) * 256 + col] = f2bf(acc[mi][ni][j]);
        }
    }
  }
}

// ---------------------------------------------------------------------------
// bf16 MFMA GEMM (layer 2): BM=32, 4 waves along N, grid (1, M/32).
// ---------------------------------------------------------------------------
template <int BN, bool AF32, bool OBF>
__global__ __launch_bounds__(256) void k_gemm_mfma(const void* __restrict__ Ap,
                                                   const unsigned short* __restrict__ BT,
                                                   void* __restrict__ Cp,
                                                   int M, int N, int K) {
  constexpr int WCOLS = BN / 4;
  constexpr int NFW = WCOLS / 16;
  __shared__ unsigned short As[32][40];
  __shared__ unsigned short Bs[BN][40];
  const int tid = threadIdx.x;
  const int row0 = blockIdx.y * 32;
  const int col0 = blockIdx.x * BN;
  const int wn = tid >> 6, lane = tid & 63;
  const int lr = lane & 15, lk = lane >> 4;
  f32x4 acc[2][NFW];
#pragma unroll
  for (int mi = 0; mi < 2; ++mi)
#pragma unroll
    for (int ni = 0; ni < NFW; ++ni) acc[mi][ni] = (f32x4)0.0f;
  const int ar = tid >> 3;
  const int aseg = (tid & 7) * 4;
  for (int k0 = 0; k0 < K; k0 += 32) {
    {
      int grow = row0 + ar;
      unsigned short a4[4] = {0, 0, 0, 0};
      if (grow < M) {
        if (AF32) {
          const float* A = (const float*)Ap;
          float4 v = *(const float4*)&A[(size_t)grow * K + k0 + aseg];
          a4[0] = f2bf(v.x); a4[1] = f2bf(v.y); a4[2] = f2bf(v.z); a4[3] = f2bf(v.w);
        } else {
          const unsigned short* A = (const unsigned short*)Ap;
          ushort4v v = *(const ushort4v*)&A[(size_t)grow * K + k0 + aseg];
          a4[0] = v[0]; a4[1] = v[1]; a4[2] = v[2]; a4[3] = v[3];
        }
      }
      *(ushort4v*)&As[ar][aseg] = *(ushort4v*)a4;
    }
#pragma unroll
    for (int p = 0; p < BN / 64; ++p) {
      int u = tid + p * 256;
      int br = u >> 2;
      int bseg = (u & 3) * 8;
      ushort8 bv = *(const ushort8*)&BT[(size_t)(col0 + br) * K + k0 + bseg];
      *(ushort8*)&Bs[br][bseg] = bv;
    }
    __syncthreads();
    short8 a[2], b[NFW];
#pragma unroll
    for (int mi = 0; mi < 2; ++mi)
      a[mi] = *(const short8*)&As[mi * 16 + lr][lk * 8];
#pragma unroll
    for (int ni = 0; ni < NFW; ++ni)
      b[ni] = *(const short8*)&Bs[wn * WCOLS + ni * 16 + lr][lk * 8];
#pragma unroll
    for (int mi = 0; mi < 2; ++mi)
#pragma unroll
      for (int ni = 0; ni < NFW; ++ni)
        acc[mi][ni] = __builtin_amdgcn_mfma_f32_16x16x32_bf16(a[mi], b[ni], acc[mi][ni], 0, 0, 0);
    __syncthreads();
  }
#pragma unroll
  for (int mi = 0; mi < 2; ++mi) {
    int rbase = row0 + mi * 16 + lk * 4;
#pragma unroll
    for (int j = 0; j < 4; ++j) {
      int row = rbase + j;
      if (row < M) {
#pragma unroll
        for (int ni = 0; ni < NFW; ++ni) {
          int col = col0 + wn * WCOLS + ni * 16 + lr;
          if (OBF) ((unsigned short*)Cp)[(size_t)row * N + col] = f2bf(acc[mi][ni][j]);
          else ((float*)Cp)[(size_t)row * N + col] = acc[mi][ni][j];
        }
      }
    }
  }
}

// ---------------------------------------------------------------------------
// Wave-per-node GCN aggregation over bf16 h (+bias, relu, jax dropout).
// ---------------------------------------------------------------------------
template <int C, bool OBF>
__global__ __launch_bounds__(256) void k_agg_bf(const unsigned short* __restrict__ h,
                                                void* __restrict__ outv,
                                                const int* __restrict__ off,
                                                const int* __restrict__ srcs,
                                                const float* __restrict__ wgt,
                                                const float* __restrict__ dinv,
                                                const float* __restrict__ bias,
                                                unsigned key0, unsigned key1, int n) {
  typedef __attribute__((ext_vector_type(C))) unsigned short ushortC;
  const int node = blockIdx.x * (blockDim.x >> 6) + (threadIdx.x >> 6);
  if (node >= n) return;
  const int lane = threadIdx.x & 63;
  const int F = 64 * C;
  const float dv = dinv[node];
  float acc[C];
  {
    ushortC r = *(const ushortC*)(h + (size_t)node * F + lane * C);
    float wv = dv * dv;
#pragma unroll
    for (int j = 0; j < C; ++j) acc[j] = bf2f(r[j]) * wv;
  }
  int e = off[node];
  const int e1 = off[node + 1];
  for (; e + 8 <= e1; e += 8) {
    int s[8]; float wv[8]; ushortC r[8];
#pragma unroll
    for (int q = 0; q < 8; ++q) s[q] = srcs[e + q];
#pragma unroll
    for (int q = 0; q < 8; ++q) wv[q] = wgt[e + q];
#pragma unroll
    for (int q = 0; q < 8; ++q) r[q] = *(const ushortC*)(h + (size_t)s[q] * F + lane * C);
#pragma unroll
    for (int q = 0; q < 8; ++q)
#pragma unroll
      for (int j = 0; j < C; ++j) acc[j] += bf2f(r[q][j]) * wv[q];
  }
  for (; e < e1; ++e) {
    int s = srcs[e];
    float wv = wgt[e];
    ushortC r = *(const ushortC*)(h + (size_t)s * F + lane * C);
#pragma unroll
    for (int j = 0; j < C; ++j) acc[j] += bf2f(r[j]) * wv;
  }
#pragma unroll
  for (int j = 0; j < C; ++j) {
    float v = acc[j] + bias[lane * C + j];
    v = fmaxf(v, 0.0f);
    unsigned i = (unsigned)(node * F + lane * C + j);
    float u = jax_uniform01(key0, key1, i);
    v = (u < 0.8f) ? (v * 1.25f) : 0.0f;
    acc[j] = v;
  }
  if (OBF) {
    unsigned short* op = (unsigned short*)outv + (size_t)node * F + lane * C;
#pragma unroll
    for (int j = 0; j < C; ++j) op[j] = f2bf(acc[j]);
  } else {
    float* op = (float*)outv + (size_t)node * F + lane * C;
#pragma unroll
    for (int j = 0; j < C; ++j) op[j] = acc[j];
  }
}

// ---------------------------------------------------------------------------
// agg2 + bias/relu/dropout(dk2) + layer-3 GEMM fused -> h3
// ---------------------------------------------------------------------------
__global__ __launch_bounds__(256) void k_agg2_g3(const unsigned short* __restrict__ h,
                                                 float* __restrict__ h3,
                                                 const int* __restrict__ off,
                                                 const int* __restrict__ srcs,
                                                 const float* __restrict__ wgt,
                                                 const float* __restrict__ dinv,
                                                 const float* __restrict__ b2,
                                                 const float* __restrict__ W3,
                                                 unsigned key0, unsigned key1, int n) {
  const int node = blockIdx.x * 4 + (threadIdx.x >> 6);
  if (node >= n) return;
  const int lane = threadIdx.x & 63;
  float w3a[10], w3b[10];
  {
    const float4* p = (const float4*)(W3 + lane * 20);
    float4 v0 = p[0], v1 = p[1], v2 = p[2], v3 = p[3], v4 = p[4];
    w3a[0] = v0.x; w3a[1] = v0.y; w3a[2] = v0.z; w3a[3] = v0.w;
    w3a[4] = v1.x; w3a[5] = v1.y; w3a[6] = v1.z; w3a[7] = v1.w;
    w3a[8] = v2.x; w3a[9] = v2.y;
    w3b[0] = v2.z; w3b[1] = v2.w;
    w3b[2] = v3.x; w3b[3] = v3.y; w3b[4] = v3.z; w3b[5] = v3.w;
    w3b[6] = v4.x; w3b[7] = v4.y; w3b[8] = v4.z; w3b[9] = v4.w;
  }
  const float dv = dinv[node];
  float acc0, acc1;
  {
    unsigned r = *(const unsigned*)(h + (size_t)node * 128 + lane * 2);
    float wv = dv * dv;
    acc0 = bf2f((unsigned short)(r & 0xffffu)) * wv;
    acc1 = bf2f((unsigned short)(r >> 16)) * wv;
  }
  int e = off[node];
  const int e1 = off[node + 1];
  for (; e + 8 <= e1; e += 8) {
    int s[8]; float wv[8]; unsigned r[8];
#pragma unroll
    for (int q = 0; q < 8; ++q) s[q] = srcs[e + q];
#pragma unroll
    for (int q = 0; q < 8; ++q) wv[q] = wgt[e + q];
#pragma unroll
    for (int q = 0; q < 8; ++q) r[q] = *(const unsigned*)(h + (size_t)s[q] * 128 + lane * 2);
#pragma unroll
    for (int q = 0; q < 8; ++q) {
      acc0 += bf2f((unsigned short)(r[q] & 0xffffu)) * wv[q];
      acc1 += bf2f((unsigned short)(r[q] >> 16)) * wv[q];
    }
  }
  for (; e < e1; ++e) {
    int s = srcs[e];
    float wv = wgt[e];
    unsigned r = *(const unsigned*)(h + (size_t)s * 128 + lane * 2);
    acc0 += bf2f((unsigned short)(r & 0xffffu)) * wv;
    acc1 += bf2f((unsigned short)(r >> 16)) * wv;
  }
  {
    float v = fmaxf(acc0 + b2[lane * 2], 0.0f);
    float u = jax_uniform01(key0, key1, (unsigned)(node * 128 + lane * 2));
    acc0 = (u < 0.8f) ? (v * 1.25f) : 0.0f;
  }
  {
    float v = fmaxf(acc1 + b2[lane * 2 + 1], 0.0f);
    float u = jax_uniform01(key0, key1, (unsigned)(node * 128 + lane * 2 + 1));
    acc1 = (u < 0.8f) ? (v * 1.25f) : 0.0f;
  }
  float myout = 0.0f;
#pragma unroll
  for (int c = 0; c < 10; ++c) {
    float part = acc0 * w3a[c] + acc1 * w3b[c];
#pragma unroll
    for (int o = 32; o; o >>= 1) part += __shfl_xor(part, o);
    if (lane == c) myout = part;
  }
  if (lane < 10) h3[(size_t)node * 10 + lane] = myout;
}

// ---------------------------------------------------------------------------
// layer 3: wave-per-node aggregate (10-dim) + bias + log_softmax.
// ---------------------------------------------------------------------------
__global__ __launch_bounds__(256) void k_agg3_lsm_v2(const float* __restrict__ h,
                                                     float* __restrict__ out,
                                                     const int* __restrict__ off,
                                                     const int* __restrict__ srcs,
                                                     const float* __restrict__ wgt,
                                                     const float* __restrict__ dinv,
                                                     const float* __restrict__ b,
                                                     int n) {
  const int node = blockIdx.x * 4 + (threadIdx.x >> 6);
  if (node >= n) return;
  const int lane = threadIdx.x & 63;
  const bool act = (lane < 10);
  const float dv = dinv[node];
  float acc = 0.0f;
  if (act) acc = h[(size_t)node * 10 + lane] * dv * dv;
  int e = off[node];
  const int e1 = off[node + 1];
  for (; e + 4 <= e1; e += 4) {
    int s0 = srcs[e + 0], s1 = srcs[e + 1], s2 = srcs[e + 2], s3 = srcs[e + 3];
    float w0 = wgt[e + 0], w1 = wgt[e + 1], w2 = wgt[e + 2], w3 = wgt[e + 3];
    if (act) {
      acc += h[(size_t)s0 * 10 + lane] * w0 + h[(size_t)s1 * 10 + lane] * w1 +
             h[(size_t)s2 * 10 + lane] * w2 + h[(size_t)s3 * 10 + lane] * w3;
    }
  }
  for (; e < e1; ++e) {
    int s = srcs[e];
    float w = wgt[e];
    if (act) acc += h[(size_t)s * 10 + lane] * w;
  }
  float v = act ? (acc + b[lane]) : -1e30f;
  float m = v;
#pragma unroll
  for (int o = 32; o; o >>= 1) m = fmaxf(m, __shfl_xor(m, o));
  float p = act ? expf(v - m) : 0.0f;
  float ssum = p;
#pragma unroll
  for (int o = 32; o; o >>= 1) ssum += __shfl_xor(ssum, o);
  float lse = m + logf(ssum);
  if (act) out[(size_t)node * 10 + lane] = v - lse;
}

// ---------------------------------------------------------------------------
extern "C" void kernel_launch(void* const* d_in, const int* in_sizes, int n_in,
                              void* d_out, int out_size, void* d_ws, size_t ws_size,
                              hipStream_t stream) {
  const float* x  = (const float*)d_in[0];
  const int*   ei = (const int*)d_in[1];
  const float* W1 = (const float*)d_in[2];
  const float* b1 = (const float*)d_in[3];
  const float* W2 = (const float*)d_in[4];
  const float* b2 = (const float*)d_in[5];
  const float* W3 = (const float*)d_in[6];
  const float* b3 = (const float*)d_in[7];
  float* out = (float*)d_out;

  const int N = 20000;
  int E = in_sizes[1] / 2;
  const int D1 = 256, D2 = 128;

  char* ws = (char*)d_ws;
  auto carve = [&](size_t bytes) -> char* {
    char* p = ws;
    ws += (bytes + 255) & ~(size_t)255;
    return p;
  };
  int*   deg  = (int*)carve((size_t)N * 4);
  int*   off  = (int*)carve((size_t)(N + 1) * 4);
  int*   cur  = (int*)carve((size_t)N * 4);
  float* dinv = (float*)carve((size_t)N * 4);
  int*   bsum = (int*)carve((size_t)128 * 4);
  int*   bar  = (int*)carve((size_t)16 * 4);
  int*   srcs = (int*)carve((size_t)E * 4);
  float* wgt  = (float*)carve((size_t)E * 4);
  unsigned short* W1T = (unsigned short*)carve((size_t)D1 * 512 * 2);
  unsigned short* W2T = (unsigned short*)carve((size_t)D2 * D1 * 2);
  unsigned short* bufHb = (unsigned short*)carve((size_t)N * D1 * 2);   // h1(bf16) then h2(bf16)
  unsigned short* bufA  = (unsigned short*)carve((size_t)N * D1 * 2);   // a1 bf16
  float* h3 = (float*)carve((size_t)N * 10 * 4);

  unsigned dk1_0, dk1_1, dk2_0, dk2_1;
  threefry2x32(0u, 1u, 0u, 0u, &dk1_0, &dk1_1);
  threefry2x32(0u, 1u, 0u, 1u, &dk2_0, &dk2_1);

  // zero the barrier counters (graph-capturable memset node)
  hipMemsetAsync(bar, 0, 16 * 4, stream);

  // prep chain ∥ GEMM1 in one dispatch
  k_front<<<PREPB + N / 32, 256, 0, stream>>>(x, ei, deg, off, cur, dinv, bsum,
                                              bar, srcs, wgt, W1, W2, W1T, W2T,
                                              bufHb, E);

  // agg1 -> a1 (bf16)
  k_agg_bf<4, true><<<(N + 3) / 4, 256, 0, stream>>>(bufHb, bufA, off, srcs, wgt,
                                                     dinv, b1, dk1_0, dk1_1, N);

  // GEMM2: h2(bf16) = a1 @ W2
  k_gemm_mfma<128, false, true><<<dim3(1, N / 32), 256, 0, stream>>>(bufA, W2T,
                                                                     bufHb, N, D2, D1);

  // agg2 + gemm3 fused -> h3
  k_agg2_g3<<<(N + 3) / 4, 256, 0, stream>>>(bufHb, h3, off, srcs, wgt, dinv,
                                             b2, W3, dk2_0, dk2_1, N);

  // layer-3 aggregation + log_softmax -> out
  k_agg3_lsm_v2<<<(N + 3) / 4, 256, 0, stream>>>(h3, out, off, srcs, wgt, dinv,
                                                 b3, N);
}

// Round 10
// 159.807 us; speedup vs baseline: 5.7062x; 2.1707x over previous
//
#include <hip/hip_runtime.h>
#include <hip/hip_bf16.h>
#include <math.h>

typedef __attribute__((ext_vector_type(8))) short short8;
typedef __attribute__((ext_vector_type(8))) unsigned short ushort8;
typedef __attribute__((ext_vector_type(4))) unsigned short ushort4v;
typedef __attribute__((ext_vector_type(4))) float f32x4;

// ---------------------------------------------------------------------------
// JAX threefry2x32 (20 rounds) — verified bit-exact vs jax.random in R1.
// ---------------------------------------------------------------------------
__host__ __device__ inline void threefry2x32(unsigned k0, unsigned k1,
                                             unsigned x0, unsigned x1,
                                             unsigned* out0, unsigned* out1) {
  unsigned ks0 = k0, ks1 = k1, ks2 = k0 ^ k1 ^ 0x1BD11BDAu;
  x0 += ks0; x1 += ks1;
#define TF_ROUND(r) { x0 += x1; x1 = (x1 << (r)) | (x1 >> (32 - (r))); x1 ^= x0; }
  TF_ROUND(13) TF_ROUND(15) TF_ROUND(26) TF_ROUND(6)
  x0 += ks1; x1 += ks2 + 1u;
  TF_ROUND(17) TF_ROUND(29) TF_ROUND(16) TF_ROUND(24)
  x0 += ks2; x1 += ks0 + 2u;
  TF_ROUND(13) TF_ROUND(15) TF_ROUND(26) TF_ROUND(6)
  x0 += ks0; x1 += ks1 + 3u;
  TF_ROUND(17) TF_ROUND(29) TF_ROUND(16) TF_ROUND(24)
  x0 += ks1; x1 += ks2 + 4u;
  TF_ROUND(13) TF_ROUND(15) TF_ROUND(26) TF_ROUND(6)
  x0 += ks2; x1 += ks0 + 5u;
#undef TF_ROUND
  *out0 = x0; *out1 = x1;
}

__device__ inline float jax_uniform01(unsigned key0, unsigned key1, unsigned i) {
  unsigned o0, o1;
  threefry2x32(key0, key1, 0u, i, &o0, &o1);
  unsigned bits = o0 ^ o1;
  return __uint_as_float((bits >> 9) | 0x3f800000u) - 1.0f;
}

__device__ inline unsigned short f2bf(float f) {
  unsigned u = __float_as_uint(f);
  u += 0x7fffu + ((u >> 16) & 1u);   // round-to-nearest-even
  return (unsigned short)(u >> 16);
}

__device__ inline float bf2f(unsigned short b) {
  return __uint_as_float(((unsigned)b) << 16);
}

// ---------------------------------------------------------------------------
// k_init: zero deg + convert W1,W2 -> transposed bf16, one launch
// ---------------------------------------------------------------------------
__global__ __launch_bounds__(256) void k_init(int* __restrict__ deg, int n,
                                              const float* __restrict__ W1,
                                              unsigned short* __restrict__ W1T,
                                              const float* __restrict__ W2,
                                              unsigned short* __restrict__ W2T) {
  const int S1 = 512 * 256, S2 = 256 * 128;
  int idx = blockIdx.x * 256 + threadIdx.x;
  if (idx < n) { deg[idx] = 0; return; }
  idx -= n;
  if (idx < S1) {
    int k = idx / 256, c = idx % 256;
    W1T[(size_t)c * 512 + k] = f2bf(W1[idx]);
    return;
  }
  idx -= S1;
  if (idx < S2) {
    int k = idx / 128, c = idx % 128;
    W2T[(size_t)c * 256 + k] = f2bf(W2[idx]);
  }
}

__global__ void k_deg(const int* __restrict__ ei, int E, int* __restrict__ deg) {
  int e = blockIdx.x * blockDim.x + threadIdx.x;
  if (e >= E) return;
  atomicAdd(&deg[ei[E + e]], 1);
}

// ---------------------------------------------------------------------------
// scatter with self-computed prefix: block c reduces deg[0 .. c*256) directly
// (deg is 80 KB, L2-hot), then intra-block scan -> off/cur/dinv. No bsum pass.
// ---------------------------------------------------------------------------
__global__ __launch_bounds__(256) void k_scatter3(const int* __restrict__ deg,
                                                  int* __restrict__ off, int* __restrict__ cur,
                                                  float* __restrict__ dinv, int n) {
  const int c = blockIdx.x;
  const int tid = threadIdx.x;
  const int lane = tid & 63, w = tid >> 6;
  __shared__ int ws[4];
  __shared__ int wsum[4];

  // block prefix: sum of deg[0 .. c*256)
  int pb = 0;
  for (int i = tid; i < c * 256; i += 256) pb += deg[i];
#pragma unroll
  for (int o = 32; o; o >>= 1) pb += __shfl_down(pb, o);
  if (lane == 0) ws[w] = pb;
  __syncthreads();
  pb = ws[0] + ws[1] + ws[2] + ws[3];

  // intra-block exclusive scan of this chunk
  int i = c * 256 + tid;
  int d = (i < n) ? deg[i] : 0;
  int inc = d;
#pragma unroll
  for (int o = 1; o < 64; o <<= 1) {
    int u = __shfl_up(inc, o);
    if (lane >= o) inc += u;
  }
  if (lane == 63) wsum[w] = inc;
  __syncthreads();
  int wbase = 0;
  for (int k = 0; k < w; ++k) wbase += wsum[k];
  int excl = inc - d + wbase + pb;
  if (i < n) {
    off[i] = excl;
    cur[i] = excl;
    dinv[i] = 1.0f / sqrtf((float)(d + 1));
    if (i == n - 1) off[n] = excl + d;
  }
}

// fill srcs + per-edge weight wgt = dinv[s]*dinv[d]
__global__ void k_fill_w(const int* __restrict__ ei, int E,
                         int* __restrict__ cur, int* __restrict__ srcs,
                         float* __restrict__ wgt, const float* __restrict__ dinv) {
  int e = blockIdx.x * blockDim.x + threadIdx.x;
  if (e >= E) return;
  int s = ei[e];
  int d = ei[E + e];
  int pos = atomicAdd(&cur[d], 1);
  srcs[pos] = s;
  wgt[pos] = dinv[s] * dinv[d];
}

// ---------------------------------------------------------------------------
// bf16 MFMA GEMM, BM=32 tiles: C[M,N] = A[M,K] @ B[K,N], B transposed bf16 [N,K].
// 4 waves side-by-side along N; each wave 32 x (BN/4); grid (1, M/32).
// ---------------------------------------------------------------------------
template <int BN, bool AF32, bool OBF>
__global__ __launch_bounds__(256) void k_gemm_mfma(const void* __restrict__ Ap,
                                                   const unsigned short* __restrict__ BT,
                                                   void* __restrict__ Cp,
                                                   int M, int N, int K) {
  constexpr int WCOLS = BN / 4;
  constexpr int NFW = WCOLS / 16;
  __shared__ unsigned short As[32][40];   // 80B rows: exact 2-way (free) on b128 reads
  __shared__ unsigned short Bs[BN][40];
  const int tid = threadIdx.x;
  const int row0 = blockIdx.y * 32;
  const int col0 = blockIdx.x * BN;
  const int wn = tid >> 6, lane = tid & 63;
  const int lr = lane & 15, lk = lane >> 4;
  f32x4 acc[2][NFW];
#pragma unroll
  for (int mi = 0; mi < 2; ++mi)
#pragma unroll
    for (int ni = 0; ni < NFW; ++ni) acc[mi][ni] = (f32x4)0.0f;
  const int ar = tid >> 3;
  const int aseg = (tid & 7) * 4;
  for (int k0 = 0; k0 < K; k0 += 32) {
    {
      int grow = row0 + ar;
      unsigned short a4[4] = {0, 0, 0, 0};
      if (grow < M) {
        if (AF32) {
          const float* A = (const float*)Ap;
          float4 v = *(const float4*)&A[(size_t)grow * K + k0 + aseg];
          a4[0] = f2bf(v.x); a4[1] = f2bf(v.y); a4[2] = f2bf(v.z); a4[3] = f2bf(v.w);
        } else {
          const unsigned short* A = (const unsigned short*)Ap;
          ushort4v v = *(const ushort4v*)&A[(size_t)grow * K + k0 + aseg];
          a4[0] = v[0]; a4[1] = v[1]; a4[2] = v[2]; a4[3] = v[3];
        }
      }
      *(ushort4v*)&As[ar][aseg] = *(ushort4v*)a4;
    }
#pragma unroll
    for (int p = 0; p < BN / 64; ++p) {
      int u = tid + p * 256;
      int br = u >> 2;
      int bseg = (u & 3) * 8;
      ushort8 bv = *(const ushort8*)&BT[(size_t)(col0 + br) * K + k0 + bseg];
      *(ushort8*)&Bs[br][bseg] = bv;
    }
    __syncthreads();
    short8 a[2], b[NFW];
#pragma unroll
    for (int mi = 0; mi < 2; ++mi)
      a[mi] = *(const short8*)&As[mi * 16 + lr][lk * 8];
#pragma unroll
    for (int ni = 0; ni < NFW; ++ni)
      b[ni] = *(const short8*)&Bs[wn * WCOLS + ni * 16 + lr][lk * 8];
#pragma unroll
    for (int mi = 0; mi < 2; ++mi)
#pragma unroll
      for (int ni = 0; ni < NFW; ++ni)
        acc[mi][ni] = __builtin_amdgcn_mfma_f32_16x16x32_bf16(a[mi], b[ni], acc[mi][ni], 0, 0, 0);
    __syncthreads();
  }
  // epilogue: C/D layout col=lane&15, row=(lane>>4)*4+reg  [m89-verified]
#pragma unroll
  for (int mi = 0; mi < 2; ++mi) {
    int rbase = row0 + mi * 16 + lk * 4;
#pragma unroll
    for (int j = 0; j < 4; ++j) {
      int row = rbase + j;
      if (row < M) {
#pragma unroll
        for (int ni = 0; ni < NFW; ++ni) {
          int col = col0 + wn * WCOLS + ni * 16 + lr;
          if (OBF) ((unsigned short*)Cp)[(size_t)row * N + col] = f2bf(acc[mi][ni][j]);
          else ((float*)Cp)[(size_t)row * N + col] = acc[mi][ni][j];
        }
      }
    }
  }
}

// ---------------------------------------------------------------------------
// Wave-per-node GCN aggregation over bf16 h (+bias, relu, jax dropout).
// C bf16 elems per lane (F = 64*C); 4 nodes per 256-thread block; unroll x8.
// ---------------------------------------------------------------------------
template <int C, bool OBF>
__global__ __launch_bounds__(256) void k_agg_bf(const unsigned short* __restrict__ h,
                                                void* __restrict__ outv,
                                                const int* __restrict__ off,
                                                const int* __restrict__ srcs,
                                                const float* __restrict__ wgt,
                                                const float* __restrict__ dinv,
                                                const float* __restrict__ bias,
                                                unsigned key0, unsigned key1, int n) {
  typedef __attribute__((ext_vector_type(C))) unsigned short ushortC;
  const int node = blockIdx.x * (blockDim.x >> 6) + (threadIdx.x >> 6);
  if (node >= n) return;
  const int lane = threadIdx.x & 63;
  const int F = 64 * C;
  const float dv = dinv[node];
  float acc[C];
  {
    ushortC r = *(const ushortC*)(h + (size_t)node * F + lane * C);
    float wv = dv * dv;
#pragma unroll
    for (int j = 0; j < C; ++j) acc[j] = bf2f(r[j]) * wv;
  }
  int e = off[node];
  const int e1 = off[node + 1];
  for (; e + 8 <= e1; e += 8) {
    int s[8]; float wv[8]; ushortC r[8];
#pragma unroll
    for (int q = 0; q < 8; ++q) s[q] = srcs[e + q];
#pragma unroll
    for (int q = 0; q < 8; ++q) wv[q] = wgt[e + q];
#pragma unroll
    for (int q = 0; q < 8; ++q) r[q] = *(const ushortC*)(h + (size_t)s[q] * F + lane * C);
#pragma unroll
    for (int q = 0; q < 8; ++q)
#pragma unroll
      for (int j = 0; j < C; ++j) acc[j] += bf2f(r[q][j]) * wv[q];
  }
  for (; e < e1; ++e) {
    int s = srcs[e];
    float wv = wgt[e];
    ushortC r = *(const ushortC*)(h + (size_t)s * F + lane * C);
#pragma unroll
    for (int j = 0; j < C; ++j) acc[j] += bf2f(r[j]) * wv;
  }
#pragma unroll
  for (int j = 0; j < C; ++j) {
    float v = acc[j] + bias[lane * C + j];
    v = fmaxf(v, 0.0f);
    unsigned i = (unsigned)(node * F + lane * C + j);
    float u = jax_uniform01(key0, key1, i);
    v = (u < 0.8f) ? (v * 1.25f) : 0.0f;
    acc[j] = v;
  }
  if (OBF) {
    unsigned short* op = (unsigned short*)outv + (size_t)node * F + lane * C;
#pragma unroll
    for (int j = 0; j < C; ++j) op[j] = f2bf(acc[j]);
  } else {
    float* op = (float*)outv + (size_t)node * F + lane * C;
#pragma unroll
    for (int j = 0; j < C; ++j) op[j] = acc[j];
  }
}

// ---------------------------------------------------------------------------
// agg2 + bias/relu/dropout(dk2) + layer-3 GEMM fused -> h3
// ---------------------------------------------------------------------------
__global__ __launch_bounds__(256) void k_agg2_g3(const unsigned short* __restrict__ h,
                                                 float* __restrict__ h3,
                                                 const int* __restrict__ off,
                                                 const int* __restrict__ srcs,
                                                 const float* __restrict__ wgt,
                                                 const float* __restrict__ dinv,
                                                 const float* __restrict__ b2,
                                                 const float* __restrict__ W3,
                                                 unsigned key0, unsigned key1, int n) {
  const int node = blockIdx.x * 4 + (threadIdx.x >> 6);
  if (node >= n) return;
  const int lane = threadIdx.x & 63;
  float w3a[10], w3b[10];
  {
    const float4* p = (const float4*)(W3 + lane * 20);
    float4 v0 = p[0], v1 = p[1], v2 = p[2], v3 = p[3], v4 = p[4];
    w3a[0] = v0.x; w3a[1] = v0.y; w3a[2] = v0.z; w3a[3] = v0.w;
    w3a[4] = v1.x; w3a[5] = v1.y; w3a[6] = v1.z; w3a[7] = v1.w;
    w3a[8] = v2.x; w3a[9] = v2.y;
    w3b[0] = v2.z; w3b[1] = v2.w;
    w3b[2] = v3.x; w3b[3] = v3.y; w3b[4] = v3.z; w3b[5] = v3.w;
    w3b[6] = v4.x; w3b[7] = v4.y; w3b[8] = v4.z; w3b[9] = v4.w;
  }
  const float dv = dinv[node];
  float acc0, acc1;
  {
    unsigned r = *(const unsigned*)(h + (size_t)node * 128 + lane * 2);
    float wv = dv * dv;
    acc0 = bf2f((unsigned short)(r & 0xffffu)) * wv;
    acc1 = bf2f((unsigned short)(r >> 16)) * wv;
  }
  int e = off[node];
  const int e1 = off[node + 1];
  for (; e + 8 <= e1; e += 8) {
    int s[8]; float wv[8]; unsigned r[8];
#pragma unroll
    for (int q = 0; q < 8; ++q) s[q] = srcs[e + q];
#pragma unroll
    for (int q = 0; q < 8; ++q) wv[q] = wgt[e + q];
#pragma unroll
    for (int q = 0; q < 8; ++q) r[q] = *(const unsigned*)(h + (size_t)s[q] * 128 + lane * 2);
#pragma unroll
    for (int q = 0; q < 8; ++q) {
      acc0 += bf2f((unsigned short)(r[q] & 0xffffu)) * wv[q];
      acc1 += bf2f((unsigned short)(r[q] >> 16)) * wv[q];
    }
  }
  for (; e < e1; ++e) {
    int s = srcs[e];
    float wv = wgt[e];
    unsigned r = *(const unsigned*)(h + (size_t)s * 128 + lane * 2);
    acc0 += bf2f((unsigned short)(r & 0xffffu)) * wv;
    acc1 += bf2f((unsigned short)(r >> 16)) * wv;
  }
  {
    float v = fmaxf(acc0 + b2[lane * 2], 0.0f);
    float u = jax_uniform01(key0, key1, (unsigned)(node * 128 + lane * 2));
    acc0 = (u < 0.8f) ? (v * 1.25f) : 0.0f;
  }
  {
    float v = fmaxf(acc1 + b2[lane * 2 + 1], 0.0f);
    float u = jax_uniform01(key0, key1, (unsigned)(node * 128 + lane * 2 + 1));
    acc1 = (u < 0.8f) ? (v * 1.25f) : 0.0f;
  }
  float myout = 0.0f;
#pragma unroll
  for (int c = 0; c < 10; ++c) {
    float part = acc0 * w3a[c] + acc1 * w3b[c];
#pragma unroll
    for (int o = 32; o; o >>= 1) part += __shfl_xor(part, o);
    if (lane == c) myout = part;
  }
  if (lane < 10) h3[(size_t)node * 10 + lane] = myout;
}

// ---------------------------------------------------------------------------
// layer 3: wave-per-node aggregate (10-dim) + bias + log_softmax.
// ---------------------------------------------------------------------------
__global__ __launch_bounds__(256) void k_agg3_lsm_v2(const float* __restrict__ h,
                                                     float* __restrict__ out,
                                                     const int* __restrict__ off,
                                                     const int* __restrict__ srcs,
                                                     const float* __restrict__ wgt,
                                                     const float* __restrict__ dinv,
                                                     const float* __restrict__ b,
                                                     int n) {
  const int node = blockIdx.x * 4 + (threadIdx.x >> 6);
  if (node >= n) return;
  const int lane = threadIdx.x & 63;
  const bool act = (lane < 10);
  const float dv = dinv[node];
  float acc = 0.0f;
  if (act) acc = h[(size_t)node * 10 + lane] * dv * dv;
  int e = off[node];
  const int e1 = off[node + 1];
  for (; e + 4 <= e1; e += 4) {
    int s0 = srcs[e + 0], s1 = srcs[e + 1], s2 = srcs[e + 2], s3 = srcs[e + 3];
    float w0 = wgt[e + 0], w1 = wgt[e + 1], w2 = wgt[e + 2], w3 = wgt[e + 3];
    if (act) {
      acc += h[(size_t)s0 * 10 + lane] * w0 + h[(size_t)s1 * 10 + lane] * w1 +
             h[(size_t)s2 * 10 + lane] * w2 + h[(size_t)s3 * 10 + lane] * w3;
    }
  }
  for (; e < e1; ++e) {
    int s = srcs[e];
    float w = wgt[e];
    if (act) acc += h[(size_t)s * 10 + lane] * w;
  }
  float v = act ? (acc + b[lane]) : -1e30f;
  float m = v;
#pragma unroll
  for (int o = 32; o; o >>= 1) m = fmaxf(m, __shfl_xor(m, o));
  float p = act ? expf(v - m) : 0.0f;
  float ssum = p;
#pragma unroll
  for (int o = 32; o; o >>= 1) ssum += __shfl_xor(ssum, o);
  float lse = m + logf(ssum);
  if (act) out[(size_t)node * 10 + lane] = v - lse;
}

// ---------------------------------------------------------------------------
extern "C" void kernel_launch(void* const* d_in, const int* in_sizes, int n_in,
                              void* d_out, int out_size, void* d_ws, size_t ws_size,
                              hipStream_t stream) {
  const float* x  = (const float*)d_in[0];
  const int*   ei = (const int*)d_in[1];
  const float* W1 = (const float*)d_in[2];
  const float* b1 = (const float*)d_in[3];
  const float* W2 = (const float*)d_in[4];
  const float* b2 = (const float*)d_in[5];
  const float* W3 = (const float*)d_in[6];
  const float* b3 = (const float*)d_in[7];
  float* out = (float*)d_out;

  const int N = 20000;
  const int E = in_sizes[1] / 2;
  const int D1 = 256, D2 = 128;
  const int NB = (N + 255) / 256;

  char* ws = (char*)d_ws;
  auto carve = [&](size_t bytes) -> char* {
    char* p = ws;
    ws += (bytes + 255) & ~(size_t)255;
    return p;
  };
  int*   deg  = (int*)carve((size_t)N * 4);
  int*   off  = (int*)carve((size_t)(N + 1) * 4);
  int*   cur  = (int*)carve((size_t)N * 4);
  float* dinv = (float*)carve((size_t)N * 4);
  int*   srcs = (int*)carve((size_t)E * 4);
  float* wgt  = (float*)carve((size_t)E * 4);
  unsigned short* W1T = (unsigned short*)carve((size_t)D1 * 512 * 2);
  unsigned short* W2T = (unsigned short*)carve((size_t)D2 * D1 * 2);
  unsigned short* bufHb = (unsigned short*)carve((size_t)N * D1 * 2);   // h1(bf16), then h2(bf16)
  unsigned short* bufA  = (unsigned short*)carve((size_t)N * D1 * 2);   // a1 bf16
  float* h3 = (float*)carve((size_t)N * 10 * 4);                        // h3 fp32

  unsigned dk1_0, dk1_1, dk2_0, dk2_1;
  threefry2x32(0u, 1u, 0u, 0u, &dk1_0, &dk1_1);
  threefry2x32(0u, 1u, 0u, 1u, &dk2_0, &dk2_1);

  // graph prep + weight conversion (9 dispatches total)
  const int INIT_ITEMS = N + 512 * 256 + 256 * 128;
  k_init<<<(INIT_ITEMS + 255) / 256, 256, 0, stream>>>(deg, N, W1, W1T, W2, W2T);
  k_deg<<<(E + 255) / 256, 256, 0, stream>>>(ei, E, deg);
  k_scatter3<<<NB, 256, 0, stream>>>(deg, off, cur, dinv, N);
  k_fill_w<<<(E + 255) / 256, 256, 0, stream>>>(ei, E, cur, srcs, wgt, dinv);

  // layer 1: h1(bf16) = x @ W1 (single pass over x) ; agg -> a1 bf16
  k_gemm_mfma<256, true, true><<<dim3(1, N / 32), 256, 0, stream>>>(x, W1T, bufHb, N, D1, 512);
  k_agg_bf<4, true><<<(N + 3) / 4, 256, 0, stream>>>(bufHb, bufA, off, srcs, wgt, dinv, b1, dk1_0, dk1_1, N);

  // layer 2: h2(bf16) = a1 @ W2 ; agg2 + gemm3 fused -> h3
  k_gemm_mfma<128, false, true><<<dim3(1, N / 32), 256, 0, stream>>>(bufA, W2T, bufHb, N, D2, D1);
  k_agg2_g3<<<(N + 3) / 4, 256, 0, stream>>>(bufHb, h3, off, srcs, wgt, dinv, b2, W3, dk2_0, dk2_1, N);

  // layer 3 aggregation + log_softmax
  k_agg3_lsm_v2<<<(N + 3) / 4, 256, 0, stream>>>(h3, out, off, srcs, wgt, dinv, b3, N);
}

// Round 11
// 152.079 us; speedup vs baseline: 5.9962x; 1.0508x over previous
//
#include <hip/hip_runtime.h>
#include <hip/hip_bf16.h>
#include <math.h>

typedef __attribute__((ext_vector_type(8))) short short8;
typedef __attribute__((ext_vector_type(8))) unsigned short ushort8;
typedef __attribute__((ext_vector_type(4))) unsigned short ushort4v;
typedef __attribute__((ext_vector_type(4))) float f32x4;

// ---------------------------------------------------------------------------
// JAX threefry2x32 (20 rounds) — verified bit-exact vs jax.random in R1.
// ---------------------------------------------------------------------------
__host__ __device__ inline void threefry2x32(unsigned k0, unsigned k1,
                                             unsigned x0, unsigned x1,
                                             unsigned* out0, unsigned* out1) {
  unsigned ks0 = k0, ks1 = k1, ks2 = k0 ^ k1 ^ 0x1BD11BDAu;
  x0 += ks0; x1 += ks1;
#define TF_ROUND(r) { x0 += x1; x1 = (x1 << (r)) | (x1 >> (32 - (r))); x1 ^= x0; }
  TF_ROUND(13) TF_ROUND(15) TF_ROUND(26) TF_ROUND(6)
  x0 += ks1; x1 += ks2 + 1u;
  TF_ROUND(17) TF_ROUND(29) TF_ROUND(16) TF_ROUND(24)
  x0 += ks2; x1 += ks0 + 2u;
  TF_ROUND(13) TF_ROUND(15) TF_ROUND(26) TF_ROUND(6)
  x0 += ks0; x1 += ks1 + 3u;
  TF_ROUND(17) TF_ROUND(29) TF_ROUND(16) TF_ROUND(24)
  x0 += ks1; x1 += ks2 + 4u;
  TF_ROUND(13) TF_ROUND(15) TF_ROUND(26) TF_ROUND(6)
  x0 += ks2; x1 += ks0 + 5u;
#undef TF_ROUND
  *out0 = x0; *out1 = x1;
}

__device__ inline float jax_uniform01(unsigned key0, unsigned key1, unsigned i) {
  unsigned o0, o1;
  threefry2x32(key0, key1, 0u, i, &o0, &o1);
  unsigned bits = o0 ^ o1;
  return __uint_as_float((bits >> 9) | 0x3f800000u) - 1.0f;
}

__device__ inline unsigned short f2bf(float f) {
  unsigned u = __float_as_uint(f);
  u += 0x7fffu + ((u >> 16) & 1u);   // round-to-nearest-even
  return (unsigned short)(u >> 16);
}

__device__ inline float bf2f(unsigned short b) {
  return __uint_as_float(((unsigned)b) << 16);
}

// ---------------------------------------------------------------------------
// k_init: zero deg + convert W1,W2 -> transposed bf16, one launch
// ---------------------------------------------------------------------------
__global__ __launch_bounds__(256) void k_init(int* __restrict__ deg, int n,
                                              const float* __restrict__ W1,
                                              unsigned short* __restrict__ W1T,
                                              const float* __restrict__ W2,
                                              unsigned short* __restrict__ W2T) {
  const int S1 = 512 * 256, S2 = 256 * 128;
  int idx = blockIdx.x * 256 + threadIdx.x;
  if (idx < n) { deg[idx] = 0; return; }
  idx -= n;
  if (idx < S1) {
    int k = idx / 256, c = idx % 256;
    W1T[(size_t)c * 512 + k] = f2bf(W1[idx]);
    return;
  }
  idx -= S1;
  if (idx < S2) {
    int k = idx / 128, c = idx % 128;
    W2T[(size_t)c * 256 + k] = f2bf(W2[idx]);
  }
}

__global__ void k_deg(const int* __restrict__ ei, int E, int* __restrict__ deg) {
  int e = blockIdx.x * blockDim.x + threadIdx.x;
  if (e >= E) return;
  atomicAdd(&deg[ei[E + e]], 1);
}

// Phase A: per-256-block sums
__global__ __launch_bounds__(256) void k_bsum(const int* __restrict__ deg,
                                              int* __restrict__ bsum, int n) {
  int i = blockIdx.x * 256 + threadIdx.x;
  int v = (i < n) ? deg[i] : 0;
#pragma unroll
  for (int o = 32; o; o >>= 1) v += __shfl_down(v, o);
  __shared__ int ws[4];
  if ((threadIdx.x & 63) == 0) ws[threadIdx.x >> 6] = v;
  __syncthreads();
  if (threadIdx.x == 0) bsum[blockIdx.x] = ws[0] + ws[1] + ws[2] + ws[3];
}

// Phase B+C fused: block base via redundant bsum prefix reduce, then
// intra-block scan -> off/cur/dinv
__global__ __launch_bounds__(256) void k_scatter2(const int* __restrict__ deg,
                                                  const int* __restrict__ bsum,
                                                  int* __restrict__ off, int* __restrict__ cur,
                                                  float* __restrict__ dinv, int n) {
  int i = blockIdx.x * 256 + threadIdx.x;
  int lane = threadIdx.x & 63, w = threadIdx.x >> 6;
  int pb = 0;
  for (int k = lane; k < blockIdx.x; k += 64) pb += bsum[k];
#pragma unroll
  for (int o = 32; o; o >>= 1) pb += __shfl_xor(pb, o);

  int d = (i < n) ? deg[i] : 0;
  int inc = d;
#pragma unroll
  for (int o = 1; o < 64; o <<= 1) {
    int u = __shfl_up(inc, o);
    if (lane >= o) inc += u;
  }
  __shared__ int wsum[4];
  if (lane == 63) wsum[w] = inc;
  __syncthreads();
  int wbase = 0;
  for (int k = 0; k < w; ++k) wbase += wsum[k];
  int excl = inc - d + wbase + pb;
  if (i < n) {
    off[i] = excl;
    cur[i] = excl;
    dinv[i] = 1.0f / sqrtf((float)(d + 1));
    if (i == n - 1) off[n] = excl + d;
  }
}

// fill srcs + per-edge weight wgt = dinv[s]*dinv[d]
__global__ void k_fill_w(const int* __restrict__ ei, int E,
                         int* __restrict__ cur, int* __restrict__ srcs,
                         float* __restrict__ wgt, const float* __restrict__ dinv) {
  int e = blockIdx.x * blockDim.x + threadIdx.x;
  if (e >= E) return;
  int s = ei[e];
  int d = ei[E + e];
  int pos = atomicAdd(&cur[d], 1);
  srcs[pos] = s;
  wgt[pos] = dinv[s] * dinv[d];
}

// ---------------------------------------------------------------------------
// bf16 MFMA GEMM, BM=32 tiles: C[M,N] = A[M,K] @ B[K,N], B transposed bf16 [N,K].
// 4 waves side-by-side along N; each wave 32 x (BN/4); grid (1, M/32).
// ---------------------------------------------------------------------------
template <int BN, bool AF32, bool OBF>
__global__ __launch_bounds__(256) void k_gemm_mfma(const void* __restrict__ Ap,
                                                   const unsigned short* __restrict__ BT,
                                                   void* __restrict__ Cp,
                                                   int M, int N, int K) {
  constexpr int WCOLS = BN / 4;       // cols per wave
  constexpr int NFW = WCOLS / 16;     // n-frags per wave
  __shared__ unsigned short As[32][40];   // 80B rows: 2-way-only conflicts (free)
  __shared__ unsigned short Bs[BN][40];
  const int tid = threadIdx.x;
  const int row0 = blockIdx.y * 32;
  const int col0 = blockIdx.x * BN;
  const int wn = tid >> 6, lane = tid & 63;
  const int lr = lane & 15, lk = lane >> 4;

  f32x4 acc[2][NFW];
#pragma unroll
  for (int mi = 0; mi < 2; ++mi)
#pragma unroll
    for (int ni = 0; ni < NFW; ++ni) acc[mi][ni] = (f32x4)0.0f;

  const int ar = tid >> 3;            // A row 0..31
  const int aseg = (tid & 7) * 4;     // 4 elems per thread

  for (int k0 = 0; k0 < K; k0 += 32) {
    // ---- stage A (32 x 32 bf16), 4 elems/thread ----
    {
      int grow = row0 + ar;
      unsigned short a4[4] = {0, 0, 0, 0};
      if (grow < M) {
        if (AF32) {
          const float* A = (const float*)Ap;
          float4 v = *(const float4*)&A[(size_t)grow * K + k0 + aseg];
          a4[0] = f2bf(v.x); a4[1] = f2bf(v.y); a4[2] = f2bf(v.z); a4[3] = f2bf(v.w);
        } else {
          const unsigned short* A = (const unsigned short*)Ap;
          ushort4v v = *(const ushort4v*)&A[(size_t)grow * K + k0 + aseg];
          a4[0] = v[0]; a4[1] = v[1]; a4[2] = v[2]; a4[3] = v[3];
        }
      }
      *(ushort4v*)&As[ar][aseg] = *(ushort4v*)a4;
    }
    // ---- stage B (BN rows of BT x 32), ushort8 per slot ----
#pragma unroll
    for (int p = 0; p < BN / 64; ++p) {
      int u = tid + p * 256;
      int br = u >> 2;
      int bseg = (u & 3) * 8;
      ushort8 bv = *(const ushort8*)&BT[(size_t)(col0 + br) * K + k0 + bseg];
      *(ushort8*)&Bs[br][bseg] = bv;
    }
    __syncthreads();

    short8 a[2], b[NFW];
#pragma unroll
    for (int mi = 0; mi < 2; ++mi)
      a[mi] = *(const short8*)&As[mi * 16 + lr][lk * 8];
#pragma unroll
    for (int ni = 0; ni < NFW; ++ni)
      b[ni] = *(const short8*)&Bs[wn * WCOLS + ni * 16 + lr][lk * 8];
#pragma unroll
    for (int mi = 0; mi < 2; ++mi)
#pragma unroll
      for (int ni = 0; ni < NFW; ++ni)
        acc[mi][ni] = __builtin_amdgcn_mfma_f32_16x16x32_bf16(a[mi], b[ni], acc[mi][ni], 0, 0, 0);
    __syncthreads();
  }

  // epilogue: C/D layout col=lane&15, row=(lane>>4)*4+reg  [m89-verified]
#pragma unroll
  for (int mi = 0; mi < 2; ++mi) {
    int rbase = row0 + mi * 16 + lk * 4;
#pragma unroll
    for (int j = 0; j < 4; ++j) {
      int row = rbase + j;
      if (row < M) {
#pragma unroll
        for (int ni = 0; ni < NFW; ++ni) {
          int col = col0 + wn * WCOLS + ni * 16 + lr;
          if (OBF) {
            ((unsigned short*)Cp)[(size_t)row * N + col] = f2bf(acc[mi][ni][j]);
          } else {
            ((float*)Cp)[(size_t)row * N + col] = acc[mi][ni][j];
          }
        }
      }
    }
  }
}

// ---------------------------------------------------------------------------
// Wave-per-node GCN aggregation over bf16 h (+bias, relu, jax dropout).
// C bf16 elems per lane (F = 64*C); 4 nodes per 256-thread block; unroll x8.
// Edge weights precomputed (streaming read).
// ---------------------------------------------------------------------------
template <int C, bool OBF>
__global__ __launch_bounds__(256) void k_agg_bf(const unsigned short* __restrict__ h,
                                                void* __restrict__ outv,
                                                const int* __restrict__ off,
                                                const int* __restrict__ srcs,
                                                const float* __restrict__ wgt,
                                                const float* __restrict__ dinv,
                                                const float* __restrict__ bias,
                                                unsigned key0, unsigned key1, int n) {
  typedef __attribute__((ext_vector_type(C))) unsigned short ushortC;
  const int node = blockIdx.x * (blockDim.x >> 6) + (threadIdx.x >> 6);
  if (node >= n) return;
  const int lane = threadIdx.x & 63;
  const int F = 64 * C;
  const float dv = dinv[node];

  float acc[C];
  {
    ushortC r = *(const ushortC*)(h + (size_t)node * F + lane * C);
    float wv = dv * dv;
#pragma unroll
    for (int j = 0; j < C; ++j) acc[j] = bf2f(r[j]) * wv;
  }
  int e = off[node];
  const int e1 = off[node + 1];
  for (; e + 8 <= e1; e += 8) {
    int s[8];
    float wv[8];
    ushortC r[8];
#pragma unroll
    for (int q = 0; q < 8; ++q) s[q] = srcs[e + q];
#pragma unroll
    for (int q = 0; q < 8; ++q) wv[q] = wgt[e + q];
#pragma unroll
    for (int q = 0; q < 8; ++q) r[q] = *(const ushortC*)(h + (size_t)s[q] * F + lane * C);
#pragma unroll
    for (int q = 0; q < 8; ++q)
#pragma unroll
      for (int j = 0; j < C; ++j) acc[j] += bf2f(r[q][j]) * wv[q];
  }
  for (; e < e1; ++e) {
    int s = srcs[e];
    float wv = wgt[e];
    ushortC r = *(const ushortC*)(h + (size_t)s * F + lane * C);
#pragma unroll
    for (int j = 0; j < C; ++j) acc[j] += bf2f(r[j]) * wv;
  }
#pragma unroll
  for (int j = 0; j < C; ++j) {
    float v = acc[j] + bias[lane * C + j];
    v = fmaxf(v, 0.0f);
    unsigned i = (unsigned)(node * F + lane * C + j);
    float u = jax_uniform01(key0, key1, i);
    v = (u < 0.8f) ? (v * 1.25f) : 0.0f;
    acc[j] = v;
  }
  if (OBF) {
    unsigned short* op = (unsigned short*)outv + (size_t)node * F + lane * C;
#pragma unroll
    for (int j = 0; j < C; ++j) op[j] = f2bf(acc[j]);
  } else {
    float* op = (float*)outv + (size_t)node * F + lane * C;
#pragma unroll
    for (int j = 0; j < C; ++j) op[j] = acc[j];
  }
}

// ---------------------------------------------------------------------------
// agg2 + layer-3 GEMM fused: aggregate h2 (bf16, 128 feat), bias+relu+dropout
// in regs, then h3[node][0..9] = a2_row @ W3 via per-lane W3 rows + butterfly.
// ---------------------------------------------------------------------------
__global__ __launch_bounds__(256) void k_agg2_g3(const unsigned short* __restrict__ h,
                                                 float* __restrict__ h3,
                                                 const int* __restrict__ off,
                                                 const int* __restrict__ srcs,
                                                 const float* __restrict__ wgt,
                                                 const float* __restrict__ dinv,
                                                 const float* __restrict__ b2,
                                                 const float* __restrict__ W3,
                                                 unsigned key0, unsigned key1, int n) {
  const int node = blockIdx.x * 4 + (threadIdx.x >> 6);
  if (node >= n) return;
  const int lane = threadIdx.x & 63;

  // W3 rows 2*lane and 2*lane+1 -> 20 regs (coalesced, L2-hot)
  float w3a[10], w3b[10];
  {
    const float4* p = (const float4*)(W3 + lane * 20);
    float4 v0 = p[0], v1 = p[1], v2 = p[2], v3 = p[3], v4 = p[4];
    w3a[0] = v0.x; w3a[1] = v0.y; w3a[2] = v0.z; w3a[3] = v0.w;
    w3a[4] = v1.x; w3a[5] = v1.y; w3a[6] = v1.z; w3a[7] = v1.w;
    w3a[8] = v2.x; w3a[9] = v2.y;
    w3b[0] = v2.z; w3b[1] = v2.w;
    w3b[2] = v3.x; w3b[3] = v3.y; w3b[4] = v3.z; w3b[5] = v3.w;
    w3b[6] = v4.x; w3b[7] = v4.y; w3b[8] = v4.z; w3b[9] = v4.w;
  }

  const float dv = dinv[node];
  float acc0, acc1;
  {
    unsigned r = *(const unsigned*)(h + (size_t)node * 128 + lane * 2);
    float wv = dv * dv;
    acc0 = bf2f((unsigned short)(r & 0xffffu)) * wv;
    acc1 = bf2f((unsigned short)(r >> 16)) * wv;
  }
  int e = off[node];
  const int e1 = off[node + 1];
  for (; e + 8 <= e1; e += 8) {
    int s[8];
    float wv[8];
    unsigned r[8];
#pragma unroll
    for (int q = 0; q < 8; ++q) s[q] = srcs[e + q];
#pragma unroll
    for (int q = 0; q < 8; ++q) wv[q] = wgt[e + q];
#pragma unroll
    for (int q = 0; q < 8; ++q) r[q] = *(const unsigned*)(h + (size_t)s[q] * 128 + lane * 2);
#pragma unroll
    for (int q = 0; q < 8; ++q) {
      acc0 += bf2f((unsigned short)(r[q] & 0xffffu)) * wv[q];
      acc1 += bf2f((unsigned short)(r[q] >> 16)) * wv[q];
    }
  }
  for (; e < e1; ++e) {
    int s = srcs[e];
    float wv = wgt[e];
    unsigned r = *(const unsigned*)(h + (size_t)s * 128 + lane * 2);
    acc0 += bf2f((unsigned short)(r & 0xffffu)) * wv;
    acc1 += bf2f((unsigned short)(r >> 16)) * wv;
  }
  // bias + relu + dropout (dk2), flat index node*128 + lane*2 + j
  {
    float v = fmaxf(acc0 + b2[lane * 2], 0.0f);
    float u = jax_uniform01(key0, key1, (unsigned)(node * 128 + lane * 2));
    acc0 = (u < 0.8f) ? (v * 1.25f) : 0.0f;
  }
  {
    float v = fmaxf(acc1 + b2[lane * 2 + 1], 0.0f);
    float u = jax_uniform01(key0, key1, (unsigned)(node * 128 + lane * 2 + 1));
    acc1 = (u < 0.8f) ? (v * 1.25f) : 0.0f;
  }
  // layer-3 GEMM: h3[c] = sum_k a2[k] * W3[k][c]
  float myout = 0.0f;
#pragma unroll
  for (int c = 0; c < 10; ++c) {
    float part = acc0 * w3a[c] + acc1 * w3b[c];
#pragma unroll
    for (int o = 32; o; o >>= 1) part += __shfl_xor(part, o);
    if (lane == c) myout = part;
  }
  if (lane < 10) h3[(size_t)node * 10 + lane] = myout;
}

// ---------------------------------------------------------------------------
// layer 3: wave-per-node aggregate (10-dim) + bias + log_softmax.
// ---------------------------------------------------------------------------
__global__ __launch_bounds__(256) void k_agg3_lsm_v2(const float* __restrict__ h,
                                                     float* __restrict__ out,
                                                     const int* __restrict__ off,
                                                     const int* __restrict__ srcs,
                                                     const float* __restrict__ wgt,
                                                     const float* __restrict__ dinv,
                                                     const float* __restrict__ b,
                                                     int n) {
  const int node = blockIdx.x * 4 + (threadIdx.x >> 6);
  if (node >= n) return;
  const int lane = threadIdx.x & 63;
  const bool act = (lane < 10);
  const float dv = dinv[node];

  float acc = 0.0f;
  if (act) acc = h[(size_t)node * 10 + lane] * dv * dv;
  int e = off[node];
  const int e1 = off[node + 1];
  for (; e + 4 <= e1; e += 4) {
    int s0 = srcs[e + 0], s1 = srcs[e + 1], s2 = srcs[e + 2], s3 = srcs[e + 3];
    float w0 = wgt[e + 0], w1 = wgt[e + 1], w2 = wgt[e + 2], w3 = wgt[e + 3];
    if (act) {
      acc += h[(size_t)s0 * 10 + lane] * w0 + h[(size_t)s1 * 10 + lane] * w1 +
             h[(size_t)s2 * 10 + lane] * w2 + h[(size_t)s3 * 10 + lane] * w3;
    }
  }
  for (; e < e1; ++e) {
    int s = srcs[e];
    float w = wgt[e];
    if (act) acc += h[(size_t)s * 10 + lane] * w;
  }
  float v = act ? (acc + b[lane]) : -1e30f;
  float m = v;
#pragma unroll
  for (int o = 32; o; o >>= 1) m = fmaxf(m, __shfl_xor(m, o));
  float p = act ? expf(v - m) : 0.0f;
  float ssum = p;
#pragma unroll
  for (int o = 32; o; o >>= 1) ssum += __shfl_xor(ssum, o);
  float lse = m + logf(ssum);
  if (act) out[(size_t)node * 10 + lane] = v - lse;
}

// ---------------------------------------------------------------------------
extern "C" void kernel_launch(void* const* d_in, const int* in_sizes, int n_in,
                              void* d_out, int out_size, void* d_ws, size_t ws_size,
                              hipStream_t stream) {
  const float* x  = (const float*)d_in[0];
  const int*   ei = (const int*)d_in[1];
  const float* W1 = (const float*)d_in[2];
  const float* b1 = (const float*)d_in[3];
  const float* W2 = (const float*)d_in[4];
  const float* b2 = (const float*)d_in[5];
  const float* W3 = (const float*)d_in[6];
  const float* b3 = (const float*)d_in[7];
  float* out = (float*)d_out;

  const int N = 20000;
  const int E = in_sizes[1] / 2;
  const int D1 = 256, D2 = 128;
  const int NB = (N + 255) / 256;   // 79 scan blocks

  char* ws = (char*)d_ws;
  auto carve = [&](size_t bytes) -> char* {
    char* p = ws;
    ws += (bytes + 255) & ~(size_t)255;
    return p;
  };
  int*   deg  = (int*)carve((size_t)N * 4);
  int*   off  = (int*)carve((size_t)(N + 1) * 4);
  int*   cur  = (int*)carve((size_t)N * 4);
  float* dinv = (float*)carve((size_t)N * 4);
  int*   bsum = (int*)carve((size_t)128 * 4);
  int*   srcs = (int*)carve((size_t)E * 4);
  float* wgt  = (float*)carve((size_t)E * 4);
  unsigned short* W1T = (unsigned short*)carve((size_t)D1 * 512 * 2);
  unsigned short* W2T = (unsigned short*)carve((size_t)D2 * D1 * 2);
  unsigned short* bufHb = (unsigned short*)carve((size_t)N * D1 * 2);   // h1(bf16), then h2(bf16)
  unsigned short* bufA_bf = (unsigned short*)carve((size_t)N * D1 * 2); // a1 bf16
  float* bufH3 = (float*)carve((size_t)N * 10 * 4);                     // h3 fp32

  unsigned dk1_0, dk1_1, dk2_0, dk2_1;
  threefry2x32(0u, 1u, 0u, 0u, &dk1_0, &dk1_1);
  threefry2x32(0u, 1u, 0u, 1u, &dk2_0, &dk2_1);

  // graph prep + weight conversion (10 dispatches total)
  const int INIT_ITEMS = N + 512 * 256 + 256 * 128;
  k_init<<<(INIT_ITEMS + 255) / 256, 256, 0, stream>>>(deg, N, W1, W1T, W2, W2T);
  k_deg<<<(E + 255) / 256, 256, 0, stream>>>(ei, E, deg);
  k_bsum<<<NB, 256, 0, stream>>>(deg, bsum, N);
  k_scatter2<<<NB, 256, 0, stream>>>(deg, bsum, off, cur, dinv, N);
  k_fill_w<<<(E + 255) / 256, 256, 0, stream>>>(ei, E, cur, srcs, wgt, dinv);

  // layer 1: h1(bf16) = x @ W1 (single pass over x) ; agg -> a1 bf16
  k_gemm_mfma<256, true, true><<<dim3(1, N / 32), 256, 0, stream>>>(x, W1T, bufHb, N, D1, 512);
  k_agg_bf<4, true><<<(N + 3) / 4, 256, 0, stream>>>(bufHb, bufA_bf, off, srcs, wgt, dinv, b1, dk1_0, dk1_1, N);

  // layer 2: h2(bf16) = a1 @ W2 ; agg2 + gemm3 fused -> h3
  k_gemm_mfma<128, false, true><<<dim3(1, N / 32), 256, 0, stream>>>(bufA_bf, W2T, bufHb, N, D2, D1);
  k_agg2_g3<<<(N + 3) / 4, 256, 0, stream>>>(bufHb, bufH3, off, srcs, wgt, dinv, b2, W3, dk2_0, dk2_1, N);

  // layer 3 aggregation + log_softmax
  k_agg3_lsm_v2<<<(N + 3) / 4, 256, 0, stream>>>(bufH3, out, off, srcs, wgt, dinv, b3, N);
}